// Round 8
// baseline (861.156 us; speedup 1.0000x reference)
//
#include <hip/hip_runtime.h>

#define NN 10000
#define CC 128
#define HH 256
#define EE 320000
#define ETILE 96
#define EBLOCKS 3334  // ceil(EE/96); pad = 64 zero-edges

typedef __bf16 bf16_t;
typedef __bf16 bf16x8 __attribute__((ext_vector_type(8)));
typedef __bf16 bf16x4 __attribute__((ext_vector_type(4)));
typedef float f32x4 __attribute__((ext_vector_type(4)));

__device__ __forceinline__ float silu_f(float v) {
#if __has_builtin(__builtin_amdgcn_rcpf)
  return v * __builtin_amdgcn_rcpf(1.0f + __expf(-v));
#else
  return v / (1.0f + __expf(-v));
#endif
}

// ---- GEMM slab helper (16x16x32 bf16 MFMA) ----
// Fragment layouts (guide §3, m89-verified):
//   1st operand: lane holds A[m=lane&15][k=quad*8+j]
//   2nd operand: lane holds B[k=quad*8+j][n=lane&15]
//   C/D: col(n)=lane&15, row(m)=quad*4+reg
template<int RE, int KD, int SA, int NT>
__device__ __forceinline__ void gemm_lg(const bf16_t* sAa, const bf16_t* __restrict__ BT,
                                        int nwavebase, int lr, int quad, f32x4 acc[RE][NT]) {
  for (int kk = 0; kk < KD; kk += 32) {
    bf16x8 a[RE]; bf16x8 b[NT];
#pragma unroll
    for (int re = 0; re < RE; re++)
      a[re] = *(const bf16x8*)(sAa + (re * 16 + lr) * SA + kk + quad * 8);
#pragma unroll
    for (int ce = 0; ce < NT; ce++)
      b[ce] = *(const bf16x8*)(BT + (size_t)(nwavebase + ce * 16 + lr) * KD + kk + quad * 8);
#pragma unroll
    for (int re = 0; re < RE; re++)
#pragma unroll
      for (int ce = 0; ce < NT; ce++)
        acc[re][ce] = __builtin_amdgcn_mfma_f32_16x16x32_bf16(a[re], b[ce], acc[re][ce], 0, 0, 0);
  }
}

// ---------- prep: 6 weight transposes + zero sums/cnt/edat-pad ----------
__global__ __launch_bounds__(256) void prep_kernel(
    const float* __restrict__ We1, const float* __restrict__ We2,
    const float* __restrict__ Wn1, const float* __restrict__ Wn2,
    const float* __restrict__ Wm1, const float* __restrict__ Wm2,
    bf16_t* __restrict__ We1T, bf16_t* __restrict__ We2T,
    bf16_t* __restrict__ Wn1T, bf16_t* __restrict__ Wn2T,
    bf16_t* __restrict__ Wm1T, bf16_t* __restrict__ Wm2T,
    float* __restrict__ sums, int* __restrict__ cnt, uint4* __restrict__ edat) {
  int i = blockIdx.x * 256 + threadIdx.x;
  if (i < 327680) {
    const float* src; bf16_t* dst; int K, Nc, idx;
    if      (i < 65536)  { src = We1; dst = We1T; K = 256; Nc = 256; idx = i; }
    else if (i < 131072) { src = We2; dst = We2T; K = 256; Nc = 256; idx = i - 65536; }
    else if (i < 229376) { src = Wn1; dst = Wn1T; K = 384; Nc = 256; idx = i - 131072; }
    else if (i < 262144) { src = Wn2; dst = Wn2T; K = 256; Nc = 128; idx = i - 229376; }
    else if (i < 294912) { src = Wm1; dst = Wm1T; K = 128; Nc = 256; idx = i - 262144; }
    else                 { src = Wm2; dst = Wm2T; K = 256; Nc = 128; idx = i - 294912; }
    int n = idx / K, k = idx - n * K;
    dst[idx] = (bf16_t)src[(size_t)k * Nc + n];
  } else if (i < 327680 + 640000) {  // NN*HH/4 f32x4 zeros
    f32x4 z = {0.f, 0.f, 0.f, 0.f};
    ((f32x4*)sums)[i - 327680] = z;
  } else if (i < 327680 + 640000 + 2500) {  // NN/4 int4 zeros
    int4 z = {0, 0, 0, 0};
    ((int4*)cnt)[i - 967680] = z;
  } else if (i < 327680 + 640000 + 2500 + 64) {  // zero pad edges
    uint4 z = {0u, 0u, 0u, 0u};
    edat[EE + (i - 970180)] = z;
  }
}

// ---------- fused LN1 + P/Q precompute, 16 nodes/block, 625 blocks ----------
// hn = LN(h,g1,bt1) -> hn16
// PQ[n][0:256]   = hn[n] @ We1[0:128,:] + be1   (P, be1 folded)
// PQ[n][256:512] = hn[n] @ We1[128:256,:]       (Q)
__global__ __launch_bounds__(256, 4) void node_pre_kernel(
    const float* __restrict__ h, const float* __restrict__ g1,
    const float* __restrict__ bt1,
    const bf16_t* __restrict__ We1T, const float* __restrict__ be1,
    bf16_t* __restrict__ hn16, bf16_t* __restrict__ PQ) {
  __shared__ __align__(16) bf16_t sHn[16 * 136];
  int tid = threadIdx.x;
  int lane = tid & 63, wave = tid >> 6;
  int lr = lane & 15, quad = lane >> 4;
  int n0 = blockIdx.x * 16;  // 625 * 16 = NN exact

  // LN1: 16 threads/node, 8 channels each
  {
    int node = tid >> 4, c0 = (tid & 15) * 8;
    size_t base = (size_t)(n0 + node) * CC;
    f32x4 u0 = *(const f32x4*)(h + base + c0);
    f32x4 u1 = *(const f32x4*)(h + base + c0 + 4);
    float s = 0.f, sq = 0.f;
#pragma unroll
    for (int j = 0; j < 4; j++) { s += u0[j] + u1[j]; sq += u0[j] * u0[j] + u1[j] * u1[j]; }
#pragma unroll
    for (int o = 8; o > 0; o >>= 1) { s += __shfl_xor(s, o); sq += __shfl_xor(sq, o); }
    float mu = s * (1.0f / CC);
    float var = sq * (1.0f / CC) - mu * mu;
    float rs = rsqrtf(var + 1e-5f);
    f32x4 gg0 = *(const f32x4*)(g1 + c0), gg1 = *(const f32x4*)(g1 + c0 + 4);
    f32x4 bb0 = *(const f32x4*)(bt1 + c0), bb1 = *(const f32x4*)(bt1 + c0 + 4);
    bf16x8 ov;
#pragma unroll
    for (int j = 0; j < 4; j++) {
      ov[j] = (bf16_t)((u0[j] - mu) * rs * gg0[j] + bb0[j]);
      ov[j + 4] = (bf16_t)((u1[j] - mu) * rs * gg1[j] + bb1[j]);
    }
    *(bf16x8*)(sHn + node * 136 + c0) = ov;
    *(bf16x8*)(hn16 + base + c0) = ov;
  }
  __syncthreads();

  // PQ GEMM: waves 0-1 -> P (We1T k-cols 0:128), waves 2-3 -> Q (k-cols 128:256).
  bool isQ = wave >= 2;
  int rbase = (wave & 1) * 128;
  int koff = isQ ? 128 : 0;
  f32x4 zf = {0.f, 0.f, 0.f, 0.f};
  f32x4 acc[8];
#pragma unroll
  for (int i = 0; i < 8; i++) acc[i] = zf;
  for (int kk = 0; kk < 128; kk += 32) {
    bf16x8 b = *(const bf16x8*)(sHn + lr * 136 + kk + quad * 8);
    bf16x8 a[8];
#pragma unroll
    for (int re = 0; re < 8; re++)
      a[re] = *(const bf16x8*)(We1T + (size_t)(rbase + re * 16 + lr) * 256 + koff + kk + quad * 8);
#pragma unroll
    for (int re = 0; re < 8; re++)
      acc[re] = __builtin_amdgcn_mfma_f32_16x16x32_bf16(a[re], b, acc[re], 0, 0, 0);
  }
  // C: col = node (lr), row = channel rbase + re*16 + quad*4 + r
#pragma unroll
  for (int re = 0; re < 8; re++) {
    int cb = rbase + re * 16 + quad * 4;
    f32x4 bb = isQ ? zf : *(const f32x4*)(be1 + cb);
    bf16x4 o;
#pragma unroll
    for (int r = 0; r < 4; r++) o[r] = (bf16_t)(acc[re][r] + bb[r]);
    *(bf16x4*)(PQ + (size_t)(n0 + lr) * 512 + (isQ ? 256 : 0) + cb) = o;
  }
}

// ---------- CSR build ----------
__global__ __launch_bounds__(256) void count_kernel(const int* __restrict__ ei, int* __restrict__ cnt) {
  int e = blockIdx.x * 256 + threadIdx.x;
  atomicAdd(&cnt[ei[EE + e]], 1);
}

// single-pass scan: thread owns 10 contiguous elements
__global__ __launch_bounds__(1024) void scan_kernel(const int* __restrict__ cnt, int* __restrict__ cursor) {
  __shared__ int wsum[16];
  int tid = threadIdx.x, wave = tid >> 6, lane = tid & 63;
  int base = tid * 10;
  int v[10]; int S = 0;
#pragma unroll
  for (int j = 0; j < 10; j++) {
    int i = base + j;
    v[j] = (i < NN) ? cnt[i] : 0;
    S += v[j];
  }
  int s = S;
#pragma unroll
  for (int off = 1; off < 64; off <<= 1) { int t = __shfl_up(s, off); if (lane >= off) s += t; }
  if (lane == 63) wsum[wave] = s;
  __syncthreads();
  if (tid < 16) {
    int ws = wsum[tid];
#pragma unroll
    for (int off = 1; off < 16; off <<= 1) { int t = __shfl_up(ws, off); if (tid >= off) ws += t; }
    wsum[tid] = ws;
  }
  __syncthreads();
  int ex = ((wave > 0) ? wsum[wave - 1] : 0) + s - S;  // exclusive prefix of this chunk
#pragma unroll
  for (int j = 0; j < 10; j++) {
    int i = base + j;
    if (i < NN) cursor[i] = ex;
    ex += v[j];
  }
}

__global__ __launch_bounds__(256) void scatter_kernel(const int* __restrict__ ei,
                                                      const float* __restrict__ x,
                                                      int* __restrict__ cursor,
                                                      uint4* __restrict__ edat) {
  int e = blockIdx.x * 256 + threadIdx.x;
  int r = ei[e], c = ei[EE + e];
  float dx = x[3 * r] - x[3 * c];
  float dy = x[3 * r + 1] - x[3 * c + 1];
  float dz = x[3 * r + 2] - x[3 * c + 2];
  float d = sqrtf(dx * dx + dy * dy + dz * dz);
  float cc = (d <= 5.0f) ? 0.5f * (cosf(d * 0.6283185307179586f) + 1.0f) : 0.0f;
  int pos = atomicAdd(&cursor[c], 1);
  uint4 v = {(unsigned)r, (unsigned)c, __float_as_uint(d), __float_as_uint(cc)};
  edat[pos] = v;
}

// ---------- edge kernel: 96-edge tiles, K-split LDS (5 blocks/CU), tile-skip reduce ----------
__global__ __launch_bounds__(256, 5) void edge_mlp_kernel(
    const uint4* __restrict__ edat, const bf16_t* __restrict__ PQ,
    const float* __restrict__ We1last,
    const bf16_t* __restrict__ We2T, const float* __restrict__ be2,
    float* __restrict__ sums) {
  __shared__ __align__(16) bf16_t sM1[ETILE * 136];  // half-K buffer: 26112 B
  __shared__ int sRow[ETILE], sCol[ETILE];
  __shared__ float sD[ETILE], sCc[ETILE];
  __shared__ unsigned long long sMaskA;
  __shared__ unsigned sMaskB;
  int tid = threadIdx.x;
  int lane = tid & 63, wave = tid >> 6;
  int lr = lane & 15, quad = lane >> 4;
  int e0 = blockIdx.x * ETILE;

  if (tid < ETILE) {
    uint4 v = edat[e0 + tid];
    sRow[tid] = (int)v.x; sCol[tid] = (int)v.y;
    sD[tid] = __uint_as_float(v.z); sCc[tid] = __uint_as_float(v.w);
  }
  __syncthreads();

  if (tid < ETILE) {
    int fl = (tid > 0) && (sCol[tid] != sCol[tid - 1]);
    unsigned long long m = __ballot(fl);
    if (tid == 0) sMaskA = m;
    if (tid == 64) sMaskB = (unsigned)m;
  }

  f32x4 zf = {0.f, 0.f, 0.f, 0.f};
  f32x4 acc[6][4];
#pragma unroll
  for (int i = 0; i < 6; i++)
#pragma unroll
    for (int j = 0; j < 4; j++) acc[i][j] = zf;

  // K-split: stage m1 half (96x128), GEMM that half, overwrite, GEMM rest.
#pragma unroll
  for (int half = 0; half < 2; half++) {
    int kbase = half * 128;
    if (half) __syncthreads();  // all waves done reading sM1's previous half

    // m1[e][kbase+k0..+7] = silu(P[row] + Q[col] + d*wl): 96 edges x 16 chunks, 6/thread
#pragma unroll
    for (int i = 0; i < 6; i++) {
      int o = tid + i * 256;
      int e = o >> 4, q = o & 15;  // q == tid&15, loop-invariant
      int k0 = q * 8;
      int row = sRow[e], col = sCol[e];
      float d = sD[e];
      bf16x8 pv = *(const bf16x8*)(PQ + (size_t)row * 512 + kbase + k0);
      bf16x8 qv = *(const bf16x8*)(PQ + (size_t)col * 512 + 256 + kbase + k0);
      f32x4 wl0 = *(const f32x4*)(We1last + kbase + k0);
      f32x4 wl1 = *(const f32x4*)(We1last + kbase + k0 + 4);
      bf16x8 m;
#pragma unroll
      for (int j = 0; j < 4; j++) {
        m[j] = (bf16_t)silu_f((float)pv[j] + (float)qv[j] + d * wl0[j]);
        m[j + 4] = (bf16_t)silu_f((float)pv[j + 4] + (float)qv[j + 4] + d * wl1[j]);
      }
      *(bf16x8*)(sM1 + e * 136 + k0) = m;
    }
    __syncthreads();

    // GEMM2 K-half: m1 (96 x 128) @ We2T rows (k-slice kbase..kbase+127)
    for (int kk = 0; kk < 128; kk += 32) {
      bf16x8 a[6]; bf16x8 b[4];
#pragma unroll
      for (int re = 0; re < 6; re++)
        a[re] = *(const bf16x8*)(sM1 + (re * 16 + lr) * 136 + kk + quad * 8);
#pragma unroll
      for (int ce = 0; ce < 4; ce++)
        b[ce] = *(const bf16x8*)(We2T + (size_t)(wave * 64 + ce * 16 + lr) * 256 + kbase + kk + quad * 8);
#pragma unroll
      for (int re = 0; re < 6; re++)
#pragma unroll
        for (int ce = 0; ce < 4; ce++)
          acc[re][ce] = __builtin_amdgcn_mfma_f32_16x16x32_bf16(a[re], b[ce], acc[re][ce], 0, 0, 0);
    }
  }

  // in-register epilogue: silu(acc+be2)*cc  (edge e = re*16+quad*4+r)
  float be2v[4];
#pragma unroll
  for (int ce = 0; ce < 4; ce++) be2v[ce] = be2[wave * 64 + ce * 16 + lr];
#pragma unroll
  for (int re = 0; re < 6; re++) {
    f32x4 cc = *(const f32x4*)(sCc + re * 16 + quad * 4);
#pragma unroll
    for (int ce = 0; ce < 4; ce++)
#pragma unroll
      for (int r = 0; r < 4; r++)
        acc[re][ce][r] = silu_f(acc[re][ce][r] + be2v[ce]) * cc[r];
  }

  // register segmented reduction with static tile-skip (wave-uniform branches).
  // 64-bit mask arithmetic throughout (lo<=95 -> shifts well-defined).
  {
    unsigned long long mA = sMaskA;
    unsigned long long mB = (unsigned long long)sMaskB;  // bit i = edge 64+i
    int lo = 0;
    while (lo < ETILE) {
      int hi;
      if (lo < 63) {
        unsigned long long t = mA & (~0ull << (lo + 1));
        hi = t ? (__ffsll((long long)t) - 1)
               : (mB ? 64 + __ffsll((long long)mB) - 1 : ETILE);
      } else {
        unsigned long long t1 = mB & (~0ull << (lo - 63));
        hi = t1 ? 64 + __ffsll((long long)t1) - 1 : ETILE;
      }
      f32x4 tv = zf;
#pragma unroll
      for (int re = 0; re < 6; re++) {
        int t0 = re * 16, t1e = t0 + 16;
        if (t1e <= lo || t0 >= hi) continue;  // tile outside segment (scalar skip)
        if (t0 >= lo && t1e <= hi) {          // tile fully inside: unmasked adds
#pragma unroll
          for (int r = 0; r < 4; r++)
#pragma unroll
            for (int ce = 0; ce < 4; ce++)
              tv[ce] += acc[re][ce][r];
        } else {                              // straddles boundary: masked adds
          int eb = t0 + quad * 4;
#pragma unroll
          for (int r = 0; r < 4; r++) {
            int e = eb + r;
            bool in = (e >= lo) && (e < hi);
#pragma unroll
            for (int ce = 0; ce < 4; ce++)
              tv[ce] += in ? acc[re][ce][r] : 0.0f;
          }
        }
      }
#pragma unroll
      for (int ce = 0; ce < 4; ce++) {
        tv[ce] += __shfl_xor(tv[ce], 16);
        tv[ce] += __shfl_xor(tv[ce], 32);
      }
      if (quad == 0) {
        int colv = sCol[lo];
#pragma unroll
        for (int ce = 0; ce < 4; ce++)
          atomicAdd(&sums[(size_t)colv * HH + wave * 64 + ce * 16 + lr], tv[ce]);
      }
      lo = hi;
    }
  }
}

// ---------- fused node pipeline: 32 nodes/block, 313 blocks ----------
__global__ __launch_bounds__(256, 2) void node_fused_kernel(
    const float* __restrict__ h, const bf16_t* __restrict__ hn16,
    const float* __restrict__ sums, const int* __restrict__ cnt,
    const bf16_t* __restrict__ Wn1T, const float* __restrict__ bn1,
    const bf16_t* __restrict__ Wn2T, const float* __restrict__ bn2,
    const float* __restrict__ g2, const float* __restrict__ bt2,
    const bf16_t* __restrict__ Wm1T, const float* __restrict__ bm1,
    const bf16_t* __restrict__ Wm2T, const float* __restrict__ bm2,
    float* __restrict__ out) {
  __shared__ __align__(16) bf16_t sA1[32 * 392];   // 25088 B
  __shared__ __align__(16) bf16_t sM[32 * 264];    // 16896 B
  __shared__ __align__(16) float sH1[32 * 132];    // 16896 B
  __shared__ __align__(16) bf16_t sLn[32 * 136];   // 8704 B
  __shared__ float sRc[32];
  int tid = threadIdx.x;
  int lane = tid & 63, wave = tid >> 6;
  int lr = lane & 15, quad = lane >> 4;
  int n0 = blockIdx.x * 32;  // 313 blocks; last has 16 live nodes

  if (tid < 32) {
    int node = n0 + tid;
    sRc[tid] = (node < NN) ? 1.0f / fmaxf((float)cnt[node], 1.0f) : 0.0f;
  }
  __syncthreads();

  // stage A1 = [hn16 | sums*rc]: 32 nodes x 48 16B-chunks, 6/thread
#pragma unroll
  for (int i = 0; i < 6; i++) {
    int o = tid + i * 256;
    int e = o / 48, q = o - e * 48;
    int node = n0 + e;
    if (q < 16) {
      uint4 v = {0u, 0u, 0u, 0u};
      if (node < NN) v = *(const uint4*)(hn16 + (size_t)node * CC + q * 8);
      *(uint4*)(sA1 + e * 392 + q * 8) = v;
    } else {
      bf16x8 bv = {};
      if (node < NN) {
        float rc = sRc[e];
        const float* sp = sums + (size_t)node * HH + (q - 16) * 8;
#pragma unroll
        for (int k2 = 0; k2 < 8; k2++) bv[k2] = (bf16_t)(sp[k2] * rc);
      }
      *(bf16x8*)(sA1 + e * 392 + 128 + (q - 16) * 8) = bv;
    }
  }
  __syncthreads();

  f32x4 zf = {0.f, 0.f, 0.f, 0.f};
  {  // GEMM1: 32x384 @ 384x256 -> silu -> sM
    f32x4 acc[2][4];
#pragma unroll
    for (int i = 0; i < 2; i++)
#pragma unroll
      for (int j = 0; j < 4; j++) acc[i][j] = zf;
    gemm_lg<2, 384, 392, 4>(sA1, Wn1T, wave * 64, lr, quad, acc);
#pragma unroll
    for (int ce = 0; ce < 4; ce++) {
      int n = wave * 64 + ce * 16 + lr;
      float b1 = bn1[n];
#pragma unroll
      for (int re = 0; re < 2; re++)
#pragma unroll
        for (int r = 0; r < 4; r++)
          sM[(re * 16 + quad * 4 + r) * 264 + n] = (bf16_t)silu_f(acc[re][ce][r] + b1);
    }
  }
  __syncthreads();

  {  // GEMM2: 32x256 @ 256x128; h1 = h + hn + hd -> sH1
    f32x4 acc[2][2];
#pragma unroll
    for (int i = 0; i < 2; i++) { acc[i][0] = zf; acc[i][1] = zf; }
    gemm_lg<2, 256, 264, 2>(sM, Wn2T, wave * 32, lr, quad, acc);
#pragma unroll
    for (int ce = 0; ce < 2; ce++) {
      int n = wave * 32 + ce * 16 + lr;
      float b2 = bn2[n];
#pragma unroll
      for (int re = 0; re < 2; re++)
#pragma unroll
        for (int r = 0; r < 4; r++) {
          int node = re * 16 + quad * 4 + r;
          float hv = 0.f;
          if (n0 + node < NN) hv = h[(size_t)(n0 + node) * CC + n];
          sH1[node * 132 + n] = hv + (float)sA1[node * 392 + n] + acc[re][ce][r] + b2;
        }
    }
  }
  __syncthreads();

  {  // LN2 in-LDS: 8 threads/node, 16 channels each
    int node = tid >> 3, c0 = (tid & 7) * 16;
    f32x4 u[4];
    float s = 0.f, sq = 0.f;
#pragma unroll
    for (int j = 0; j < 4; j++) {
      u[j] = *(const f32x4*)(sH1 + node * 132 + c0 + j * 4);
#pragma unroll
      for (int r = 0; r < 4; r++) { s += u[j][r]; sq += u[j][r] * u[j][r]; }
    }
    s += __shfl_xor(s, 1); sq += __shfl_xor(sq, 1);
    s += __shfl_xor(s, 2); sq += __shfl_xor(sq, 2);
    s += __shfl_xor(s, 4); sq += __shfl_xor(sq, 4);
    float mu = s * (1.0f / CC);
    float var = sq * (1.0f / CC) - mu * mu;
    float rs = rsqrtf(var + 1e-5f);
#pragma unroll
    for (int j2 = 0; j2 < 2; j2++) {
      f32x4 gg0 = *(const f32x4*)(g2 + c0 + j2 * 8);
      f32x4 gg1 = *(const f32x4*)(g2 + c0 + j2 * 8 + 4);
      f32x4 bb0 = *(const f32x4*)(bt2 + c0 + j2 * 8);
      f32x4 bb1 = *(const f32x4*)(bt2 + c0 + j2 * 8 + 4);
      bf16x8 ov;
#pragma unroll
      for (int r = 0; r < 4; r++) {
        ov[r] = (bf16_t)((u[j2 * 2][r] - mu) * rs * gg0[r] + bb0[r]);
        ov[r + 4] = (bf16_t)((u[j2 * 2 + 1][r] - mu) * rs * gg1[r] + bb1[r]);
      }
      *(bf16x8*)(sLn + node * 136 + c0 + j2 * 8) = ov;
    }
  }
  __syncthreads();

  {  // GEMM3: 32x128 @ 128x256 -> silu -> sM (reuse)
    f32x4 acc[2][4];
#pragma unroll
    for (int i = 0; i < 2; i++)
#pragma unroll
      for (int j = 0; j < 4; j++) acc[i][j] = zf;
    gemm_lg<2, 128, 136, 4>(sLn, Wm1T, wave * 64, lr, quad, acc);
#pragma unroll
    for (int ce = 0; ce < 4; ce++) {
      int n = wave * 64 + ce * 16 + lr;
      float b1 = bm1[n];
#pragma unroll
      for (int re = 0; re < 2; re++)
#pragma unroll
        for (int r = 0; r < 4; r++)
          sM[(re * 16 + quad * 4 + r) * 264 + n] = (bf16_t)silu_f(acc[re][ce][r] + b1);
    }
  }
  __syncthreads();

  {  // GEMM4: 32x256 @ 256x128; out = h1 + hd2
    f32x4 acc[2][2];
#pragma unroll
    for (int i = 0; i < 2; i++) { acc[i][0] = zf; acc[i][1] = zf; }
    gemm_lg<2, 256, 264, 2>(sM, Wm2T, wave * 32, lr, quad, acc);
#pragma unroll
    for (int ce = 0; ce < 2; ce++) {
      int n = wave * 32 + ce * 16 + lr;
      float b2 = bm2[n];
#pragma unroll
      for (int re = 0; re < 2; re++)
#pragma unroll
        for (int r = 0; r < 4; r++) {
          int node = re * 16 + quad * 4 + r;
          if (n0 + node < NN)
            out[(size_t)(n0 + node) * CC + n] = sH1[node * 132 + n] + acc[re][ce][r] + b2;
        }
    }
  }
}

extern "C" void kernel_launch(void* const* d_in, const int* in_sizes, int n_in,
                              void* d_out, int out_size, void* d_ws, size_t ws_size,
                              hipStream_t stream) {
  const float* x    = (const float*)d_in[0];
  const float* h    = (const float*)d_in[1];
  const int*   ei   = (const int*)d_in[2];
  const float* We1  = (const float*)d_in[3];
  const float* be1  = (const float*)d_in[4];
  const float* We2  = (const float*)d_in[5];
  const float* be2  = (const float*)d_in[6];
  const float* Wn1  = (const float*)d_in[7];
  const float* bn1  = (const float*)d_in[8];
  const float* Wn2  = (const float*)d_in[9];
  const float* bn2  = (const float*)d_in[10];
  const float* Wm1  = (const float*)d_in[11];
  const float* bm1  = (const float*)d_in[12];
  const float* Wm2  = (const float*)d_in[13];
  const float* bm2  = (const float*)d_in[14];
  const float* g1   = (const float*)d_in[15];
  const float* bt1  = (const float*)d_in[16];
  const float* g2   = (const float*)d_in[17];
  const float* bt2  = (const float*)d_in[18];
  float* out = (float*)d_out;

  char* wp = (char*)d_ws;
  size_t off = 0;
  auto alloc = [&](size_t bytes) -> void* {
    void* p = wp + off;
    off = (off + bytes + 255) & ~(size_t)255;
    return p;
  };

  bf16_t* hn16   = (bf16_t*)alloc((size_t)NN * CC * 2);
  bf16_t* PQ     = (bf16_t*)alloc((size_t)NN * 512 * 2);
  float*  sums   = (float*)alloc((size_t)NN * HH * 4);
  int*    cnt    = (int*)alloc((size_t)NN * 4);
  int*    cursor = (int*)alloc((size_t)NN * 4);
  uint4*  edat   = (uint4*)alloc((size_t)(EBLOCKS * ETILE) * 16);
  bf16_t* We1T   = (bf16_t*)alloc(256 * 256 * 2);
  bf16_t* We2T   = (bf16_t*)alloc(256 * 256 * 2);
  bf16_t* Wn1T   = (bf16_t*)alloc(256 * 384 * 2);
  bf16_t* Wn2T   = (bf16_t*)alloc(128 * 256 * 2);
  bf16_t* Wm1T   = (bf16_t*)alloc(256 * 128 * 2);
  bf16_t* Wm2T   = (bf16_t*)alloc(128 * 256 * 2);

  prep_kernel<<<3791, 256, 0, stream>>>(We1, We2, Wn1, Wn2, Wm1, Wm2,
                                        We1T, We2T, Wn1T, Wn2T, Wm1T, Wm2T,
                                        sums, cnt, edat);

  node_pre_kernel<<<NN / 16, 256, 0, stream>>>(h, g1, bt1, We1T, be1, hn16, PQ);

  count_kernel<<<EE / 256, 256, 0, stream>>>(ei, cnt);
  scan_kernel<<<1, 1024, 0, stream>>>(cnt, cursor);
  scatter_kernel<<<EE / 256, 256, 0, stream>>>(ei, x, cursor, edat);

  edge_mlp_kernel<<<EBLOCKS, 256, 0, stream>>>(edat, PQ, We1 + 256 * 256,
                                               We2T, be2, sums);

  node_fused_kernel<<<(NN + 31) / 32, 256, 0, stream>>>(h, hn16, sums, cnt,
                                                        Wn1T, bn1, Wn2T, bn2,
                                                        g2, bt2, Wm1T, bm1, Wm2T, bm2, out);
}

// Round 9
// 342.184 us; speedup vs baseline: 2.5166x; 2.5166x over previous
//
#include <hip/hip_runtime.h>

#define NN 10000
#define CC 128
#define HH 256
#define EE 320000
#define ETILE 96
#define EBLOCKS 3334  // ceil(EE/96); pad = 64 zero-edges

typedef __bf16 bf16_t;
typedef __bf16 bf16x8 __attribute__((ext_vector_type(8)));
typedef __bf16 bf16x4 __attribute__((ext_vector_type(4)));
typedef float f32x4 __attribute__((ext_vector_type(4)));

__device__ __forceinline__ float silu_f(float v) {
#if __has_builtin(__builtin_amdgcn_rcpf)
  return v * __builtin_amdgcn_rcpf(1.0f + __expf(-v));
#else
  return v / (1.0f + __expf(-v));
#endif
}

// ---- GEMM slab helper (16x16x32 bf16 MFMA) ----
// Fragment layouts (guide §3, m89-verified):
//   1st operand: lane holds A[m=lane&15][k=quad*8+j]
//   2nd operand: lane holds B[k=quad*8+j][n=lane&15]
//   C/D: col(n)=lane&15, row(m)=quad*4+reg
template<int RE, int KD, int SA, int NT>
__device__ __forceinline__ void gemm_lg(const bf16_t* sAa, const bf16_t* __restrict__ BT,
                                        int nwavebase, int lr, int quad, f32x4 acc[RE][NT]) {
  for (int kk = 0; kk < KD; kk += 32) {
    bf16x8 a[RE]; bf16x8 b[NT];
#pragma unroll
    for (int re = 0; re < RE; re++)
      a[re] = *(const bf16x8*)(sAa + (re * 16 + lr) * SA + kk + quad * 8);
#pragma unroll
    for (int ce = 0; ce < NT; ce++)
      b[ce] = *(const bf16x8*)(BT + (size_t)(nwavebase + ce * 16 + lr) * KD + kk + quad * 8);
#pragma unroll
    for (int re = 0; re < RE; re++)
#pragma unroll
      for (int ce = 0; ce < NT; ce++)
        acc[re][ce] = __builtin_amdgcn_mfma_f32_16x16x32_bf16(a[re], b[ce], acc[re][ce], 0, 0, 0);
  }
}

// ---------- prep: 6 weight transposes + zero sums/cnt/edat-pad ----------
__global__ __launch_bounds__(256) void prep_kernel(
    const float* __restrict__ We1, const float* __restrict__ We2,
    const float* __restrict__ Wn1, const float* __restrict__ Wn2,
    const float* __restrict__ Wm1, const float* __restrict__ Wm2,
    bf16_t* __restrict__ We1T, bf16_t* __restrict__ We2T,
    bf16_t* __restrict__ Wn1T, bf16_t* __restrict__ Wn2T,
    bf16_t* __restrict__ Wm1T, bf16_t* __restrict__ Wm2T,
    float* __restrict__ sums, int* __restrict__ cnt, uint4* __restrict__ edat) {
  int i = blockIdx.x * 256 + threadIdx.x;
  if (i < 327680) {
    const float* src; bf16_t* dst; int K, Nc, idx;
    if      (i < 65536)  { src = We1; dst = We1T; K = 256; Nc = 256; idx = i; }
    else if (i < 131072) { src = We2; dst = We2T; K = 256; Nc = 256; idx = i - 65536; }
    else if (i < 229376) { src = Wn1; dst = Wn1T; K = 384; Nc = 256; idx = i - 131072; }
    else if (i < 262144) { src = Wn2; dst = Wn2T; K = 256; Nc = 128; idx = i - 229376; }
    else if (i < 294912) { src = Wm1; dst = Wm1T; K = 128; Nc = 256; idx = i - 262144; }
    else                 { src = Wm2; dst = Wm2T; K = 256; Nc = 128; idx = i - 294912; }
    int n = idx / K, k = idx - n * K;
    dst[idx] = (bf16_t)src[(size_t)k * Nc + n];
  } else if (i < 327680 + 640000) {  // NN*HH/4 f32x4 zeros
    f32x4 z = {0.f, 0.f, 0.f, 0.f};
    ((f32x4*)sums)[i - 327680] = z;
  } else if (i < 327680 + 640000 + 2500) {  // NN/4 int4 zeros
    int4 z = {0, 0, 0, 0};
    ((int4*)cnt)[i - 967680] = z;
  } else if (i < 327680 + 640000 + 2500 + 64) {  // zero pad edges
    uint4 z = {0u, 0u, 0u, 0u};
    edat[EE + (i - 970180)] = z;
  }
}

// ---------- fused LN1 + P/Q precompute, 16 nodes/block, 625 blocks ----------
// hn = LN(h,g1,bt1) -> hn16
// PQ[n][0:256]   = hn[n] @ We1[0:128,:] + be1   (P, be1 folded)
// PQ[n][256:512] = hn[n] @ We1[128:256,:]       (Q)
__global__ __launch_bounds__(256, 4) void node_pre_kernel(
    const float* __restrict__ h, const float* __restrict__ g1,
    const float* __restrict__ bt1,
    const bf16_t* __restrict__ We1T, const float* __restrict__ be1,
    bf16_t* __restrict__ hn16, bf16_t* __restrict__ PQ) {
  __shared__ __align__(16) bf16_t sHn[16 * 136];
  int tid = threadIdx.x;
  int lane = tid & 63, wave = tid >> 6;
  int lr = lane & 15, quad = lane >> 4;
  int n0 = blockIdx.x * 16;  // 625 * 16 = NN exact

  // LN1: 16 threads/node, 8 channels each
  {
    int node = tid >> 4, c0 = (tid & 15) * 8;
    size_t base = (size_t)(n0 + node) * CC;
    f32x4 u0 = *(const f32x4*)(h + base + c0);
    f32x4 u1 = *(const f32x4*)(h + base + c0 + 4);
    float s = 0.f, sq = 0.f;
#pragma unroll
    for (int j = 0; j < 4; j++) { s += u0[j] + u1[j]; sq += u0[j] * u0[j] + u1[j] * u1[j]; }
#pragma unroll
    for (int o = 8; o > 0; o >>= 1) { s += __shfl_xor(s, o); sq += __shfl_xor(sq, o); }
    float mu = s * (1.0f / CC);
    float var = sq * (1.0f / CC) - mu * mu;
    float rs = rsqrtf(var + 1e-5f);
    f32x4 gg0 = *(const f32x4*)(g1 + c0), gg1 = *(const f32x4*)(g1 + c0 + 4);
    f32x4 bb0 = *(const f32x4*)(bt1 + c0), bb1 = *(const f32x4*)(bt1 + c0 + 4);
    bf16x8 ov;
#pragma unroll
    for (int j = 0; j < 4; j++) {
      ov[j] = (bf16_t)((u0[j] - mu) * rs * gg0[j] + bb0[j]);
      ov[j + 4] = (bf16_t)((u1[j] - mu) * rs * gg1[j] + bb1[j]);
    }
    *(bf16x8*)(sHn + node * 136 + c0) = ov;
    *(bf16x8*)(hn16 + base + c0) = ov;
  }
  __syncthreads();

  // PQ GEMM: waves 0-1 -> P (We1T k-cols 0:128), waves 2-3 -> Q (k-cols 128:256).
  bool isQ = wave >= 2;
  int rbase = (wave & 1) * 128;
  int koff = isQ ? 128 : 0;
  f32x4 zf = {0.f, 0.f, 0.f, 0.f};
  f32x4 acc[8];
#pragma unroll
  for (int i = 0; i < 8; i++) acc[i] = zf;
  for (int kk = 0; kk < 128; kk += 32) {
    bf16x8 b = *(const bf16x8*)(sHn + lr * 136 + kk + quad * 8);
    bf16x8 a[8];
#pragma unroll
    for (int re = 0; re < 8; re++)
      a[re] = *(const bf16x8*)(We1T + (size_t)(rbase + re * 16 + lr) * 256 + koff + kk + quad * 8);
#pragma unroll
    for (int re = 0; re < 8; re++)
      acc[re] = __builtin_amdgcn_mfma_f32_16x16x32_bf16(a[re], b, acc[re], 0, 0, 0);
  }
  // C: col = node (lr), row = channel rbase + re*16 + quad*4 + r
#pragma unroll
  for (int re = 0; re < 8; re++) {
    int cb = rbase + re * 16 + quad * 4;
    f32x4 bb = isQ ? zf : *(const f32x4*)(be1 + cb);
    bf16x4 o;
#pragma unroll
    for (int r = 0; r < 4; r++) o[r] = (bf16_t)(acc[re][r] + bb[r]);
    *(bf16x4*)(PQ + (size_t)(n0 + lr) * 512 + (isQ ? 256 : 0) + cb) = o;
  }
}

// ---------- CSR build ----------
__global__ __launch_bounds__(256) void count_kernel(const int* __restrict__ ei, int* __restrict__ cnt) {
  int e = blockIdx.x * 256 + threadIdx.x;
  atomicAdd(&cnt[ei[EE + e]], 1);
}

// single-pass scan: thread owns 10 contiguous elements
__global__ __launch_bounds__(1024) void scan_kernel(const int* __restrict__ cnt, int* __restrict__ cursor) {
  __shared__ int wsum[16];
  int tid = threadIdx.x, wave = tid >> 6, lane = tid & 63;
  int base = tid * 10;
  int v[10]; int S = 0;
#pragma unroll
  for (int j = 0; j < 10; j++) {
    int i = base + j;
    v[j] = (i < NN) ? cnt[i] : 0;
    S += v[j];
  }
  int s = S;
#pragma unroll
  for (int off = 1; off < 64; off <<= 1) { int t = __shfl_up(s, off); if (lane >= off) s += t; }
  if (lane == 63) wsum[wave] = s;
  __syncthreads();
  if (tid < 16) {
    int ws = wsum[tid];
#pragma unroll
    for (int off = 1; off < 16; off <<= 1) { int t = __shfl_up(ws, off); if (tid >= off) ws += t; }
    wsum[tid] = ws;
  }
  __syncthreads();
  int ex = ((wave > 0) ? wsum[wave - 1] : 0) + s - S;  // exclusive prefix of this chunk
#pragma unroll
  for (int j = 0; j < 10; j++) {
    int i = base + j;
    if (i < NN) cursor[i] = ex;
    ex += v[j];
  }
}

__global__ __launch_bounds__(256) void scatter_kernel(const int* __restrict__ ei,
                                                      const float* __restrict__ x,
                                                      int* __restrict__ cursor,
                                                      uint4* __restrict__ edat) {
  int e = blockIdx.x * 256 + threadIdx.x;
  int r = ei[e], c = ei[EE + e];
  float dx = x[3 * r] - x[3 * c];
  float dy = x[3 * r + 1] - x[3 * c + 1];
  float dz = x[3 * r + 2] - x[3 * c + 2];
  float d = sqrtf(dx * dx + dy * dy + dz * dz);
  float cc = (d <= 5.0f) ? 0.5f * (cosf(d * 0.6283185307179586f) + 1.0f) : 0.0f;
  int pos = atomicAdd(&cursor[c], 1);
  uint4 v = {(unsigned)r, (unsigned)c, __float_as_uint(d), __float_as_uint(cc)};
  edat[pos] = v;
}

// ---------- edge kernel: 96-edge tiles, K-split LDS, tile-skip reduce ----------
// launch_bounds min-waves stays at 3: it is an ALLOCATOR hint, not occupancy.
// (R8's (256,5) squeezed the budget to ~102 regs -> acc[6][4] spilled to
// scratch -> 3 GB/dispatch HBM traffic.) With 28 KB LDS, HW occupancy is
// LDS-capped at 5 blocks/CU while regs (~180/wave) allow 8 -> we get 5 free.
__global__ __launch_bounds__(256, 3) void edge_mlp_kernel(
    const uint4* __restrict__ edat, const bf16_t* __restrict__ PQ,
    const float* __restrict__ We1last,
    const bf16_t* __restrict__ We2T, const float* __restrict__ be2,
    float* __restrict__ sums) {
  __shared__ __align__(16) bf16_t sM1[ETILE * 136];  // half-K buffer: 26112 B
  __shared__ int sRow[ETILE], sCol[ETILE];
  __shared__ float sD[ETILE], sCc[ETILE];
  __shared__ unsigned long long sMaskA;
  __shared__ unsigned sMaskB;
  int tid = threadIdx.x;
  int lane = tid & 63, wave = tid >> 6;
  int lr = lane & 15, quad = lane >> 4;
  int e0 = blockIdx.x * ETILE;

  if (tid < ETILE) {
    uint4 v = edat[e0 + tid];
    sRow[tid] = (int)v.x; sCol[tid] = (int)v.y;
    sD[tid] = __uint_as_float(v.z); sCc[tid] = __uint_as_float(v.w);
  }
  __syncthreads();

  if (tid < ETILE) {
    int fl = (tid > 0) && (sCol[tid] != sCol[tid - 1]);
    unsigned long long m = __ballot(fl);
    if (tid == 0) sMaskA = m;
    if (tid == 64) sMaskB = (unsigned)m;
  }

  f32x4 zf = {0.f, 0.f, 0.f, 0.f};
  f32x4 acc[6][4];
#pragma unroll
  for (int i = 0; i < 6; i++)
#pragma unroll
    for (int j = 0; j < 4; j++) acc[i][j] = zf;

  // K-split: stage m1 half (96x128), GEMM that half, overwrite, GEMM rest.
#pragma unroll
  for (int half = 0; half < 2; half++) {
    int kbase = half * 128;
    if (half) __syncthreads();  // all waves done reading sM1's previous half

    // m1[e][kbase+k0..+7] = silu(P[row] + Q[col] + d*wl): 96 edges x 16 chunks, 6/thread
#pragma unroll
    for (int i = 0; i < 6; i++) {
      int o = tid + i * 256;
      int e = o >> 4, q = o & 15;  // q == tid&15, loop-invariant
      int k0 = q * 8;
      int row = sRow[e], col = sCol[e];
      float d = sD[e];
      bf16x8 pv = *(const bf16x8*)(PQ + (size_t)row * 512 + kbase + k0);
      bf16x8 qv = *(const bf16x8*)(PQ + (size_t)col * 512 + 256 + kbase + k0);
      f32x4 wl0 = *(const f32x4*)(We1last + kbase + k0);
      f32x4 wl1 = *(const f32x4*)(We1last + kbase + k0 + 4);
      bf16x8 m;
#pragma unroll
      for (int j = 0; j < 4; j++) {
        m[j] = (bf16_t)silu_f((float)pv[j] + (float)qv[j] + d * wl0[j]);
        m[j + 4] = (bf16_t)silu_f((float)pv[j + 4] + (float)qv[j + 4] + d * wl1[j]);
      }
      *(bf16x8*)(sM1 + e * 136 + k0) = m;
    }
    __syncthreads();

    // GEMM2 K-half: m1 (96 x 128) @ We2T rows (k-slice kbase..kbase+127)
    for (int kk = 0; kk < 128; kk += 32) {
      bf16x8 a[6]; bf16x8 b[4];
#pragma unroll
      for (int re = 0; re < 6; re++)
        a[re] = *(const bf16x8*)(sM1 + (re * 16 + lr) * 136 + kk + quad * 8);
#pragma unroll
      for (int ce = 0; ce < 4; ce++)
        b[ce] = *(const bf16x8*)(We2T + (size_t)(wave * 64 + ce * 16 + lr) * 256 + kbase + kk + quad * 8);
#pragma unroll
      for (int re = 0; re < 6; re++)
#pragma unroll
        for (int ce = 0; ce < 4; ce++)
          acc[re][ce] = __builtin_amdgcn_mfma_f32_16x16x32_bf16(a[re], b[ce], acc[re][ce], 0, 0, 0);
    }
  }

  // in-register epilogue: silu(acc+be2)*cc  (edge e = re*16+quad*4+r)
  float be2v[4];
#pragma unroll
  for (int ce = 0; ce < 4; ce++) be2v[ce] = be2[wave * 64 + ce * 16 + lr];
#pragma unroll
  for (int re = 0; re < 6; re++) {
    f32x4 cc = *(const f32x4*)(sCc + re * 16 + quad * 4);
#pragma unroll
    for (int ce = 0; ce < 4; ce++)
#pragma unroll
      for (int r = 0; r < 4; r++)
        acc[re][ce][r] = silu_f(acc[re][ce][r] + be2v[ce]) * cc[r];
  }

  // register segmented reduction with static tile-skip (wave-uniform branches).
  // 64-bit mask arithmetic throughout (lo<=95 -> shifts well-defined).
  {
    unsigned long long mA = sMaskA;
    unsigned long long mB = (unsigned long long)sMaskB;  // bit i = edge 64+i
    int lo = 0;
    while (lo < ETILE) {
      int hi;
      if (lo < 63) {
        unsigned long long t = mA & (~0ull << (lo + 1));
        hi = t ? (__ffsll((long long)t) - 1)
               : (mB ? 64 + __ffsll((long long)mB) - 1 : ETILE);
      } else {
        unsigned long long t1 = mB & (~0ull << (lo - 63));
        hi = t1 ? 64 + __ffsll((long long)t1) - 1 : ETILE;
      }
      f32x4 tv = zf;
#pragma unroll
      for (int re = 0; re < 6; re++) {
        int t0 = re * 16, t1e = t0 + 16;
        if (t1e <= lo || t0 >= hi) continue;  // tile outside segment (scalar skip)
        if (t0 >= lo && t1e <= hi) {          // tile fully inside: unmasked adds
#pragma unroll
          for (int r = 0; r < 4; r++)
#pragma unroll
            for (int ce = 0; ce < 4; ce++)
              tv[ce] += acc[re][ce][r];
        } else {                              // straddles boundary: masked adds
          int eb = t0 + quad * 4;
#pragma unroll
          for (int r = 0; r < 4; r++) {
            int e = eb + r;
            bool in = (e >= lo) && (e < hi);
#pragma unroll
            for (int ce = 0; ce < 4; ce++)
              tv[ce] += in ? acc[re][ce][r] : 0.0f;
          }
        }
      }
#pragma unroll
      for (int ce = 0; ce < 4; ce++) {
        tv[ce] += __shfl_xor(tv[ce], 16);
        tv[ce] += __shfl_xor(tv[ce], 32);
      }
      if (quad == 0) {
        int colv = sCol[lo];
#pragma unroll
        for (int ce = 0; ce < 4; ce++)
          atomicAdd(&sums[(size_t)colv * HH + wave * 64 + ce * 16 + lr], tv[ce]);
      }
      lo = hi;
    }
  }
}

// ---------- fused node pipeline: 32 nodes/block, 313 blocks ----------
__global__ __launch_bounds__(256, 2) void node_fused_kernel(
    const float* __restrict__ h, const bf16_t* __restrict__ hn16,
    const float* __restrict__ sums, const int* __restrict__ cnt,
    const bf16_t* __restrict__ Wn1T, const float* __restrict__ bn1,
    const bf16_t* __restrict__ Wn2T, const float* __restrict__ bn2,
    const float* __restrict__ g2, const float* __restrict__ bt2,
    const bf16_t* __restrict__ Wm1T, const float* __restrict__ bm1,
    const bf16_t* __restrict__ Wm2T, const float* __restrict__ bm2,
    float* __restrict__ out) {
  __shared__ __align__(16) bf16_t sA1[32 * 392];   // 25088 B
  __shared__ __align__(16) bf16_t sM[32 * 264];    // 16896 B
  __shared__ __align__(16) float sH1[32 * 132];    // 16896 B
  __shared__ __align__(16) bf16_t sLn[32 * 136];   // 8704 B
  __shared__ float sRc[32];
  int tid = threadIdx.x;
  int lane = tid & 63, wave = tid >> 6;
  int lr = lane & 15, quad = lane >> 4;
  int n0 = blockIdx.x * 32;  // 313 blocks; last has 16 live nodes

  if (tid < 32) {
    int node = n0 + tid;
    sRc[tid] = (node < NN) ? 1.0f / fmaxf((float)cnt[node], 1.0f) : 0.0f;
  }
  __syncthreads();

  // stage A1 = [hn16 | sums*rc]: 32 nodes x 48 16B-chunks, 6/thread
#pragma unroll
  for (int i = 0; i < 6; i++) {
    int o = tid + i * 256;
    int e = o / 48, q = o - e * 48;
    int node = n0 + e;
    if (q < 16) {
      uint4 v = {0u, 0u, 0u, 0u};
      if (node < NN) v = *(const uint4*)(hn16 + (size_t)node * CC + q * 8);
      *(uint4*)(sA1 + e * 392 + q * 8) = v;
    } else {
      bf16x8 bv = {};
      if (node < NN) {
        float rc = sRc[e];
        const float* sp = sums + (size_t)node * HH + (q - 16) * 8;
#pragma unroll
        for (int k2 = 0; k2 < 8; k2++) bv[k2] = (bf16_t)(sp[k2] * rc);
      }
      *(bf16x8*)(sA1 + e * 392 + 128 + (q - 16) * 8) = bv;
    }
  }
  __syncthreads();

  f32x4 zf = {0.f, 0.f, 0.f, 0.f};
  {  // GEMM1: 32x384 @ 384x256 -> silu -> sM
    f32x4 acc[2][4];
#pragma unroll
    for (int i = 0; i < 2; i++)
#pragma unroll
      for (int j = 0; j < 4; j++) acc[i][j] = zf;
    gemm_lg<2, 384, 392, 4>(sA1, Wn1T, wave * 64, lr, quad, acc);
#pragma unroll
    for (int ce = 0; ce < 4; ce++) {
      int n = wave * 64 + ce * 16 + lr;
      float b1 = bn1[n];
#pragma unroll
      for (int re = 0; re < 2; re++)
#pragma unroll
        for (int r = 0; r < 4; r++)
          sM[(re * 16 + quad * 4 + r) * 264 + n] = (bf16_t)silu_f(acc[re][ce][r] + b1);
    }
  }
  __syncthreads();

  {  // GEMM2: 32x256 @ 256x128; h1 = h + hn + hd -> sH1
    f32x4 acc[2][2];
#pragma unroll
    for (int i = 0; i < 2; i++) { acc[i][0] = zf; acc[i][1] = zf; }
    gemm_lg<2, 256, 264, 2>(sM, Wn2T, wave * 32, lr, quad, acc);
#pragma unroll
    for (int ce = 0; ce < 2; ce++) {
      int n = wave * 32 + ce * 16 + lr;
      float b2 = bn2[n];
#pragma unroll
      for (int re = 0; re < 2; re++)
#pragma unroll
        for (int r = 0; r < 4; r++) {
          int node = re * 16 + quad * 4 + r;
          float hv = 0.f;
          if (n0 + node < NN) hv = h[(size_t)(n0 + node) * CC + n];
          sH1[node * 132 + n] = hv + (float)sA1[node * 392 + n] + acc[re][ce][r] + b2;
        }
    }
  }
  __syncthreads();

  {  // LN2 in-LDS: 8 threads/node, 16 channels each
    int node = tid >> 3, c0 = (tid & 7) * 16;
    f32x4 u[4];
    float s = 0.f, sq = 0.f;
#pragma unroll
    for (int j = 0; j < 4; j++) {
      u[j] = *(const f32x4*)(sH1 + node * 132 + c0 + j * 4);
#pragma unroll
      for (int r = 0; r < 4; r++) { s += u[j][r]; sq += u[j][r] * u[j][r]; }
    }
    s += __shfl_xor(s, 1); sq += __shfl_xor(sq, 1);
    s += __shfl_xor(s, 2); sq += __shfl_xor(sq, 2);
    s += __shfl_xor(s, 4); sq += __shfl_xor(sq, 4);
    float mu = s * (1.0f / CC);
    float var = sq * (1.0f / CC) - mu * mu;
    float rs = rsqrtf(var + 1e-5f);
#pragma unroll
    for (int j2 = 0; j2 < 2; j2++) {
      f32x4 gg0 = *(const f32x4*)(g2 + c0 + j2 * 8);
      f32x4 gg1 = *(const f32x4*)(g2 + c0 + j2 * 8 + 4);
      f32x4 bb0 = *(const f32x4*)(bt2 + c0 + j2 * 8);
      f32x4 bb1 = *(const f32x4*)(bt2 + c0 + j2 * 8 + 4);
      bf16x8 ov;
#pragma unroll
      for (int r = 0; r < 4; r++) {
        ov[r] = (bf16_t)((u[j2 * 2][r] - mu) * rs * gg0[r] + bb0[r]);
        ov[r + 4] = (bf16_t)((u[j2 * 2 + 1][r] - mu) * rs * gg1[r] + bb1[r]);
      }
      *(bf16x8*)(sLn + node * 136 + c0 + j2 * 8) = ov;
    }
  }
  __syncthreads();

  {  // GEMM3: 32x128 @ 128x256 -> silu -> sM (reuse)
    f32x4 acc[2][4];
#pragma unroll
    for (int i = 0; i < 2; i++)
#pragma unroll
      for (int j = 0; j < 4; j++) acc[i][j] = zf;
    gemm_lg<2, 128, 136, 4>(sLn, Wm1T, wave * 64, lr, quad, acc);
#pragma unroll
    for (int ce = 0; ce < 4; ce++) {
      int n = wave * 64 + ce * 16 + lr;
      float b1 = bm1[n];
#pragma unroll
      for (int re = 0; re < 2; re++)
#pragma unroll
        for (int r = 0; r < 4; r++)
          sM[(re * 16 + quad * 4 + r) * 264 + n] = (bf16_t)silu_f(acc[re][ce][r] + b1);
    }
  }
  __syncthreads();

  {  // GEMM4: 32x256 @ 256x128; out = h1 + hd2
    f32x4 acc[2][2];
#pragma unroll
    for (int i = 0; i < 2; i++) { acc[i][0] = zf; acc[i][1] = zf; }
    gemm_lg<2, 256, 264, 2>(sM, Wm2T, wave * 32, lr, quad, acc);
#pragma unroll
    for (int ce = 0; ce < 2; ce++) {
      int n = wave * 32 + ce * 16 + lr;
      float b2 = bm2[n];
#pragma unroll
      for (int re = 0; re < 2; re++)
#pragma unroll
        for (int r = 0; r < 4; r++) {
          int node = re * 16 + quad * 4 + r;
          if (n0 + node < NN)
            out[(size_t)(n0 + node) * CC + n] = sH1[node * 132 + n] + acc[re][ce][r] + b2;
        }
    }
  }
}

extern "C" void kernel_launch(void* const* d_in, const int* in_sizes, int n_in,
                              void* d_out, int out_size, void* d_ws, size_t ws_size,
                              hipStream_t stream) {
  const float* x    = (const float*)d_in[0];
  const float* h    = (const float*)d_in[1];
  const int*   ei   = (const int*)d_in[2];
  const float* We1  = (const float*)d_in[3];
  const float* be1  = (const float*)d_in[4];
  const float* We2  = (const float*)d_in[5];
  const float* be2  = (const float*)d_in[6];
  const float* Wn1  = (const float*)d_in[7];
  const float* bn1  = (const float*)d_in[8];
  const float* Wn2  = (const float*)d_in[9];
  const float* bn2  = (const float*)d_in[10];
  const float* Wm1  = (const float*)d_in[11];
  const float* bm1  = (const float*)d_in[12];
  const float* Wm2  = (const float*)d_in[13];
  const float* bm2  = (const float*)d_in[14];
  const float* g1   = (const float*)d_in[15];
  const float* bt1  = (const float*)d_in[16];
  const float* g2   = (const float*)d_in[17];
  const float* bt2  = (const float*)d_in[18];
  float* out = (float*)d_out;

  char* wp = (char*)d_ws;
  size_t off = 0;
  auto alloc = [&](size_t bytes) -> void* {
    void* p = wp + off;
    off = (off + bytes + 255) & ~(size_t)255;
    return p;
  };

  bf16_t* hn16   = (bf16_t*)alloc((size_t)NN * CC * 2);
  bf16_t* PQ     = (bf16_t*)alloc((size_t)NN * 512 * 2);
  float*  sums   = (float*)alloc((size_t)NN * HH * 4);
  int*    cnt    = (int*)alloc((size_t)NN * 4);
  int*    cursor = (int*)alloc((size_t)NN * 4);
  uint4*  edat   = (uint4*)alloc((size_t)(EBLOCKS * ETILE) * 16);
  bf16_t* We1T   = (bf16_t*)alloc(256 * 256 * 2);
  bf16_t* We2T   = (bf16_t*)alloc(256 * 256 * 2);
  bf16_t* Wn1T   = (bf16_t*)alloc(256 * 384 * 2);
  bf16_t* Wn2T   = (bf16_t*)alloc(128 * 256 * 2);
  bf16_t* Wm1T   = (bf16_t*)alloc(256 * 128 * 2);
  bf16_t* Wm2T   = (bf16_t*)alloc(128 * 256 * 2);

  prep_kernel<<<3791, 256, 0, stream>>>(We1, We2, Wn1, Wn2, Wm1, Wm2,
                                        We1T, We2T, Wn1T, Wn2T, Wm1T, Wm2T,
                                        sums, cnt, edat);

  node_pre_kernel<<<NN / 16, 256, 0, stream>>>(h, g1, bt1, We1T, be1, hn16, PQ);

  count_kernel<<<EE / 256, 256, 0, stream>>>(ei, cnt);
  scan_kernel<<<1, 1024, 0, stream>>>(cnt, cursor);
  scatter_kernel<<<EE / 256, 256, 0, stream>>>(ei, x, cursor, edat);

  edge_mlp_kernel<<<EBLOCKS, 256, 0, stream>>>(edat, PQ, We1 + 256 * 256,
                                               We2T, be2, sums);

  node_fused_kernel<<<(NN + 31) / 32, 256, 0, stream>>>(h, hn16, sums, cnt,
                                                        Wn1T, bn1, Wn2T, bn2,
                                                        g2, bt2, Wm1T, bm1, Wm2T, bm2, out);
}

// Round 10
// 311.750 us; speedup vs baseline: 2.7623x; 1.0976x over previous
//
#include <hip/hip_runtime.h>

#define NN 10000
#define CC 128
#define HH 256
#define EE 320000
#define ETILE 96
#define EBLOCKS 3334  // ceil(EE/96); pad = 64 zero-edges

typedef __bf16 bf16_t;
typedef __bf16 bf16x8 __attribute__((ext_vector_type(8)));
typedef __bf16 bf16x4 __attribute__((ext_vector_type(4)));
typedef float f32x4 __attribute__((ext_vector_type(4)));

__device__ __forceinline__ float silu_f(float v) {
#if __has_builtin(__builtin_amdgcn_rcpf)
  return v * __builtin_amdgcn_rcpf(1.0f + __expf(-v));
#else
  return v / (1.0f + __expf(-v));
#endif
}

// ---- GEMM slab helper (16x16x32 bf16 MFMA) ----
// Fragment layouts (guide §3, m89-verified):
//   1st operand: lane holds A[m=lane&15][k=quad*8+j]
//   2nd operand: lane holds B[k=quad*8+j][n=lane&15]
//   C/D: col(n)=lane&15, row(m)=quad*4+reg
template<int RE, int KD, int SA, int NT>
__device__ __forceinline__ void gemm_lg(const bf16_t* sAa, const bf16_t* __restrict__ BT,
                                        int nwavebase, int lr, int quad, f32x4 acc[RE][NT]) {
  for (int kk = 0; kk < KD; kk += 32) {
    bf16x8 a[RE]; bf16x8 b[NT];
#pragma unroll
    for (int re = 0; re < RE; re++)
      a[re] = *(const bf16x8*)(sAa + (re * 16 + lr) * SA + kk + quad * 8);
#pragma unroll
    for (int ce = 0; ce < NT; ce++)
      b[ce] = *(const bf16x8*)(BT + (size_t)(nwavebase + ce * 16 + lr) * KD + kk + quad * 8);
#pragma unroll
    for (int re = 0; re < RE; re++)
#pragma unroll
      for (int ce = 0; ce < NT; ce++)
        acc[re][ce] = __builtin_amdgcn_mfma_f32_16x16x32_bf16(a[re], b[ce], acc[re][ce], 0, 0, 0);
  }
}

// ---------- prep: 6 weight transposes + zero sums/cnt/edat-pad ----------
__global__ __launch_bounds__(256) void prep_kernel(
    const float* __restrict__ We1, const float* __restrict__ We2,
    const float* __restrict__ Wn1, const float* __restrict__ Wn2,
    const float* __restrict__ Wm1, const float* __restrict__ Wm2,
    bf16_t* __restrict__ We1T, bf16_t* __restrict__ We2T,
    bf16_t* __restrict__ Wn1T, bf16_t* __restrict__ Wn2T,
    bf16_t* __restrict__ Wm1T, bf16_t* __restrict__ Wm2T,
    float* __restrict__ sums, int* __restrict__ cnt, uint4* __restrict__ edat) {
  int i = blockIdx.x * 256 + threadIdx.x;
  if (i < 327680) {
    const float* src; bf16_t* dst; int K, Nc, idx;
    if      (i < 65536)  { src = We1; dst = We1T; K = 256; Nc = 256; idx = i; }
    else if (i < 131072) { src = We2; dst = We2T; K = 256; Nc = 256; idx = i - 65536; }
    else if (i < 229376) { src = Wn1; dst = Wn1T; K = 384; Nc = 256; idx = i - 131072; }
    else if (i < 262144) { src = Wn2; dst = Wn2T; K = 256; Nc = 128; idx = i - 229376; }
    else if (i < 294912) { src = Wm1; dst = Wm1T; K = 128; Nc = 256; idx = i - 262144; }
    else                 { src = Wm2; dst = Wm2T; K = 256; Nc = 128; idx = i - 294912; }
    int n = idx / K, k = idx - n * K;
    dst[idx] = (bf16_t)src[(size_t)k * Nc + n];
  } else if (i < 327680 + 640000) {  // NN*HH/4 f32x4 zeros
    f32x4 z = {0.f, 0.f, 0.f, 0.f};
    ((f32x4*)sums)[i - 327680] = z;
  } else if (i < 327680 + 640000 + 2500) {  // NN/4 int4 zeros
    int4 z = {0, 0, 0, 0};
    ((int4*)cnt)[i - 967680] = z;
  } else if (i < 327680 + 640000 + 2500 + 64) {  // zero pad edges
    uint4 z = {0u, 0u, 0u, 0u};
    edat[EE + (i - 970180)] = z;
  }
}

// ---------- fused LN1 + P/Q precompute, 16 nodes/block, 625 blocks ----------
__global__ __launch_bounds__(256, 4) void node_pre_kernel(
    const float* __restrict__ h, const float* __restrict__ g1,
    const float* __restrict__ bt1,
    const bf16_t* __restrict__ We1T, const float* __restrict__ be1,
    bf16_t* __restrict__ hn16, bf16_t* __restrict__ PQ) {
  __shared__ __align__(16) bf16_t sHn[16 * 136];
  int tid = threadIdx.x;
  int lane = tid & 63, wave = tid >> 6;
  int lr = lane & 15, quad = lane >> 4;
  int n0 = blockIdx.x * 16;  // 625 * 16 = NN exact

  // LN1: 16 threads/node, 8 channels each
  {
    int node = tid >> 4, c0 = (tid & 15) * 8;
    size_t base = (size_t)(n0 + node) * CC;
    f32x4 u0 = *(const f32x4*)(h + base + c0);
    f32x4 u1 = *(const f32x4*)(h + base + c0 + 4);
    float s = 0.f, sq = 0.f;
#pragma unroll
    for (int j = 0; j < 4; j++) { s += u0[j] + u1[j]; sq += u0[j] * u0[j] + u1[j] * u1[j]; }
#pragma unroll
    for (int o = 8; o > 0; o >>= 1) { s += __shfl_xor(s, o); sq += __shfl_xor(sq, o); }
    float mu = s * (1.0f / CC);
    float var = sq * (1.0f / CC) - mu * mu;
    float rs = rsqrtf(var + 1e-5f);
    f32x4 gg0 = *(const f32x4*)(g1 + c0), gg1 = *(const f32x4*)(g1 + c0 + 4);
    f32x4 bb0 = *(const f32x4*)(bt1 + c0), bb1 = *(const f32x4*)(bt1 + c0 + 4);
    bf16x8 ov;
#pragma unroll
    for (int j = 0; j < 4; j++) {
      ov[j] = (bf16_t)((u0[j] - mu) * rs * gg0[j] + bb0[j]);
      ov[j + 4] = (bf16_t)((u1[j] - mu) * rs * gg1[j] + bb1[j]);
    }
    *(bf16x8*)(sHn + node * 136 + c0) = ov;
    *(bf16x8*)(hn16 + base + c0) = ov;
  }
  __syncthreads();

  // PQ GEMM: waves 0-1 -> P (We1T k-cols 0:128), waves 2-3 -> Q (k-cols 128:256).
  bool isQ = wave >= 2;
  int rbase = (wave & 1) * 128;
  int koff = isQ ? 128 : 0;
  f32x4 zf = {0.f, 0.f, 0.f, 0.f};
  f32x4 acc[8];
#pragma unroll
  for (int i = 0; i < 8; i++) acc[i] = zf;
  for (int kk = 0; kk < 128; kk += 32) {
    bf16x8 b = *(const bf16x8*)(sHn + lr * 136 + kk + quad * 8);
    bf16x8 a[8];
#pragma unroll
    for (int re = 0; re < 8; re++)
      a[re] = *(const bf16x8*)(We1T + (size_t)(rbase + re * 16 + lr) * 256 + koff + kk + quad * 8);
#pragma unroll
    for (int re = 0; re < 8; re++)
      acc[re] = __builtin_amdgcn_mfma_f32_16x16x32_bf16(a[re], b, acc[re], 0, 0, 0);
  }
  // C: col = node (lr), row = channel rbase + re*16 + quad*4 + r
#pragma unroll
  for (int re = 0; re < 8; re++) {
    int cb = rbase + re * 16 + quad * 4;
    f32x4 bb = isQ ? zf : *(const f32x4*)(be1 + cb);
    bf16x4 o;
#pragma unroll
    for (int r = 0; r < 4; r++) o[r] = (bf16_t)(acc[re][r] + bb[r]);
    *(bf16x4*)(PQ + (size_t)(n0 + lr) * 512 + (isQ ? 256 : 0) + cb) = o;
  }
}

// ---------- CSR build ----------
__global__ __launch_bounds__(256) void count_kernel(const int* __restrict__ ei, int* __restrict__ cnt) {
  int e = blockIdx.x * 256 + threadIdx.x;
  atomicAdd(&cnt[ei[EE + e]], 1);
}

// single-pass scan: thread owns 10 contiguous elements
__global__ __launch_bounds__(1024) void scan_kernel(const int* __restrict__ cnt, int* __restrict__ cursor) {
  __shared__ int wsum[16];
  int tid = threadIdx.x, wave = tid >> 6, lane = tid & 63;
  int base = tid * 10;
  int v[10]; int S = 0;
#pragma unroll
  for (int j = 0; j < 10; j++) {
    int i = base + j;
    v[j] = (i < NN) ? cnt[i] : 0;
    S += v[j];
  }
  int s = S;
#pragma unroll
  for (int off = 1; off < 64; off <<= 1) { int t = __shfl_up(s, off); if (lane >= off) s += t; }
  if (lane == 63) wsum[wave] = s;
  __syncthreads();
  if (tid < 16) {
    int ws = wsum[tid];
#pragma unroll
    for (int off = 1; off < 16; off <<= 1) { int t = __shfl_up(ws, off); if (tid >= off) ws += t; }
    wsum[tid] = ws;
  }
  __syncthreads();
  int ex = ((wave > 0) ? wsum[wave - 1] : 0) + s - S;  // exclusive prefix of this chunk
#pragma unroll
  for (int j = 0; j < 10; j++) {
    int i = base + j;
    if (i < NN) cursor[i] = ex;
    ex += v[j];
  }
}

__global__ __launch_bounds__(256) void scatter_kernel(const int* __restrict__ ei,
                                                      const float* __restrict__ x,
                                                      int* __restrict__ cursor,
                                                      uint4* __restrict__ edat) {
  int e = blockIdx.x * 256 + threadIdx.x;
  int r = ei[e], c = ei[EE + e];
  float dx = x[3 * r] - x[3 * c];
  float dy = x[3 * r + 1] - x[3 * c + 1];
  float dz = x[3 * r + 2] - x[3 * c + 2];
  float d = sqrtf(dx * dx + dy * dy + dz * dz);
  float cc = (d <= 5.0f) ? 0.5f * (cosf(d * 0.6283185307179586f) + 1.0f) : 0.0f;
  int pos = atomicAdd(&cursor[c], 1);
  uint4 v = {(unsigned)r, (unsigned)c, __float_as_uint(d), __float_as_uint(cc)};
  edat[pos] = v;
}

// ---------- edge kernel: R7 structure (full-K m1, no K-split), block-offset param ----------
// Register accounting: acc[6][4]=96 AGPR + ~84 VGPR ≈ 180/wave -> 3 waves/SIMD
// (register-capped); 52.7 KB LDS caps at 3 blocks/CU — caps coincide, no spill
// under (256,3) because staging completes BEFORE acc goes live.
__global__ __launch_bounds__(256, 3) void edge_mlp_kernel(
    const uint4* __restrict__ edat, const bf16_t* __restrict__ PQ,
    const float* __restrict__ We1last,
    const bf16_t* __restrict__ We2T, const float* __restrict__ be2,
    float* __restrict__ sums, int blk0) {
  __shared__ __align__(16) bf16_t sM1[ETILE * 264];  // 50688 B
  __shared__ int sRow[ETILE], sCol[ETILE];
  __shared__ float sD[ETILE], sCc[ETILE];
  __shared__ unsigned long long sMaskA;
  __shared__ unsigned sMaskB;
  int tid = threadIdx.x;
  int lane = tid & 63, wave = tid >> 6;
  int lr = lane & 15, quad = lane >> 4;
  int e0 = (blk0 + blockIdx.x) * ETILE;

  if (tid < ETILE) {
    uint4 v = edat[e0 + tid];
    sRow[tid] = (int)v.x; sCol[tid] = (int)v.y;
    sD[tid] = __uint_as_float(v.z); sCc[tid] = __uint_as_float(v.w);
  }
  __syncthreads();

  if (tid < ETILE) {
    int fl = (tid > 0) && (sCol[tid] != sCol[tid - 1]);
    unsigned long long m = __ballot(fl);
    if (tid == 0) sMaskA = m;
    if (tid == 64) sMaskB = (unsigned)m;
  }

  // m1[e][k] = silu(P[row][k] + Q[col][k] + d*wl[k])  (96 edges x 32 8-ch chunks)
#pragma unroll
  for (int i = 0; i < ETILE * 32 / 256; i++) {  // 12
    int o = tid + i * 256;
    int e = o >> 5, q = o & 31;
    int k0 = q * 8;
    int row = sRow[e], col = sCol[e];
    float d = sD[e];
    bf16x8 pv = *(const bf16x8*)(PQ + (size_t)row * 512 + k0);
    bf16x8 qv = *(const bf16x8*)(PQ + (size_t)col * 512 + 256 + k0);
    f32x4 wl0 = *(const f32x4*)(We1last + k0);
    f32x4 wl1 = *(const f32x4*)(We1last + k0 + 4);
    bf16x8 m;
#pragma unroll
    for (int j = 0; j < 4; j++) {
      m[j] = (bf16_t)silu_f((float)pv[j] + (float)qv[j] + d * wl0[j]);
      m[j + 4] = (bf16_t)silu_f((float)pv[j + 4] + (float)qv[j + 4] + d * wl1[j]);
    }
    *(bf16x8*)(sM1 + e * 264 + k0) = m;
  }
  __syncthreads();

  // GEMM2: m1 (96 x 256) @ We2 -> wave's 64 channels
  f32x4 zf = {0.f, 0.f, 0.f, 0.f};
  f32x4 acc[6][4];
#pragma unroll
  for (int i = 0; i < 6; i++)
#pragma unroll
    for (int j = 0; j < 4; j++) acc[i][j] = zf;
  gemm_lg<6, 256, 264, 4>(sM1, We2T, wave * 64, lr, quad, acc);

  // in-register epilogue: silu(acc+be2)*cc  (edge e = re*16+quad*4+r)
  float be2v[4];
#pragma unroll
  for (int ce = 0; ce < 4; ce++) be2v[ce] = be2[wave * 64 + ce * 16 + lr];
#pragma unroll
  for (int re = 0; re < 6; re++) {
    f32x4 cc = *(const f32x4*)(sCc + re * 16 + quad * 4);
#pragma unroll
    for (int ce = 0; ce < 4; ce++)
#pragma unroll
      for (int r = 0; r < 4; r++)
        acc[re][ce][r] = silu_f(acc[re][ce][r] + be2v[ce]) * cc[r];
  }

  // register segmented reduction with static tile-skip (wave-uniform branches).
  // 64-bit mask arithmetic throughout (lo<=95 -> shifts well-defined).
  {
    unsigned long long mA = sMaskA;
    unsigned long long mB = (unsigned long long)sMaskB;  // bit i = edge 64+i
    int lo = 0;
    while (lo < ETILE) {
      int hi;
      if (lo < 63) {
        unsigned long long t = mA & (~0ull << (lo + 1));
        hi = t ? (__ffsll((long long)t) - 1)
               : (mB ? 64 + __ffsll((long long)mB) - 1 : ETILE);
      } else {
        unsigned long long t1 = mB & (~0ull << (lo - 63));
        hi = t1 ? 64 + __ffsll((long long)t1) - 1 : ETILE;
      }
      f32x4 tv = zf;
#pragma unroll
      for (int re = 0; re < 6; re++) {
        int t0 = re * 16, t1e = t0 + 16;
        if (t1e <= lo || t0 >= hi) continue;  // tile outside segment (scalar skip)
        if (t0 >= lo && t1e <= hi) {          // tile fully inside: unmasked adds
#pragma unroll
          for (int r = 0; r < 4; r++)
#pragma unroll
            for (int ce = 0; ce < 4; ce++)
              tv[ce] += acc[re][ce][r];
        } else {                              // straddles boundary: masked adds
          int eb = t0 + quad * 4;
#pragma unroll
          for (int r = 0; r < 4; r++) {
            int e = eb + r;
            bool in = (e >= lo) && (e < hi);
#pragma unroll
            for (int ce = 0; ce < 4; ce++)
              tv[ce] += in ? acc[re][ce][r] : 0.0f;
          }
        }
      }
#pragma unroll
      for (int ce = 0; ce < 4; ce++) {
        tv[ce] += __shfl_xor(tv[ce], 16);
        tv[ce] += __shfl_xor(tv[ce], 32);
      }
      if (quad == 0) {
        int colv = sCol[lo];
#pragma unroll
        for (int ce = 0; ce < 4; ce++)
          atomicAdd(&sums[(size_t)colv * HH + wave * 64 + ce * 16 + lr], tv[ce]);
      }
      lo = hi;
    }
  }
}

// ---------- fused node pipeline: 32 nodes/block, 313 blocks ----------
__global__ __launch_bounds__(256, 2) void node_fused_kernel(
    const float* __restrict__ h, const bf16_t* __restrict__ hn16,
    const float* __restrict__ sums, const int* __restrict__ cnt,
    const bf16_t* __restrict__ Wn1T, const float* __restrict__ bn1,
    const bf16_t* __restrict__ Wn2T, const float* __restrict__ bn2,
    const float* __restrict__ g2, const float* __restrict__ bt2,
    const bf16_t* __restrict__ Wm1T, const float* __restrict__ bm1,
    const bf16_t* __restrict__ Wm2T, const float* __restrict__ bm2,
    float* __restrict__ out) {
  __shared__ __align__(16) bf16_t sA1[32 * 392];   // 25088 B
  __shared__ __align__(16) bf16_t sM[32 * 264];    // 16896 B
  __shared__ __align__(16) float sH1[32 * 132];    // 16896 B
  __shared__ __align__(16) bf16_t sLn[32 * 136];   // 8704 B
  __shared__ float sRc[32];
  int tid = threadIdx.x;
  int lane = tid & 63, wave = tid >> 6;
  int lr = lane & 15, quad = lane >> 4;
  int n0 = blockIdx.x * 32;  // 313 blocks; last has 16 live nodes

  if (tid < 32) {
    int node = n0 + tid;
    sRc[tid] = (node < NN) ? 1.0f / fmaxf((float)cnt[node], 1.0f) : 0.0f;
  }
  __syncthreads();

  // stage A1 = [hn16 | sums*rc]: 32 nodes x 48 16B-chunks, 6/thread
#pragma unroll
  for (int i = 0; i < 6; i++) {
    int o = tid + i * 256;
    int e = o / 48, q = o - e * 48;
    int node = n0 + e;
    if (q < 16) {
      uint4 v = {0u, 0u, 0u, 0u};
      if (node < NN) v = *(const uint4*)(hn16 + (size_t)node * CC + q * 8);
      *(uint4*)(sA1 + e * 392 + q * 8) = v;
    } else {
      bf16x8 bv = {};
      if (node < NN) {
        float rc = sRc[e];
        const float* sp = sums + (size_t)node * HH + (q - 16) * 8;
#pragma unroll
        for (int k2 = 0; k2 < 8; k2++) bv[k2] = (bf16_t)(sp[k2] * rc);
      }
      *(bf16x8*)(sA1 + e * 392 + 128 + (q - 16) * 8) = bv;
    }
  }
  __syncthreads();

  f32x4 zf = {0.f, 0.f, 0.f, 0.f};
  {  // GEMM1: 32x384 @ 384x256 -> silu -> sM
    f32x4 acc[2][4];
#pragma unroll
    for (int i = 0; i < 2; i++)
#pragma unroll
      for (int j = 0; j < 4; j++) acc[i][j] = zf;
    gemm_lg<2, 384, 392, 4>(sA1, Wn1T, wave * 64, lr, quad, acc);
#pragma unroll
    for (int ce = 0; ce < 4; ce++) {
      int n = wave * 64 + ce * 16 + lr;
      float b1 = bn1[n];
#pragma unroll
      for (int re = 0; re < 2; re++)
#pragma unroll
        for (int r = 0; r < 4; r++)
          sM[(re * 16 + quad * 4 + r) * 264 + n] = (bf16_t)silu_f(acc[re][ce][r] + b1);
    }
  }
  __syncthreads();

  {  // GEMM2: 32x256 @ 256x128; h1 = h + hn + hd -> sH1
    f32x4 acc[2][2];
#pragma unroll
    for (int i = 0; i < 2; i++) { acc[i][0] = zf; acc[i][1] = zf; }
    gemm_lg<2, 256, 264, 2>(sM, Wn2T, wave * 32, lr, quad, acc);
#pragma unroll
    for (int ce = 0; ce < 2; ce++) {
      int n = wave * 32 + ce * 16 + lr;
      float b2 = bn2[n];
#pragma unroll
      for (int re = 0; re < 2; re++)
#pragma unroll
        for (int r = 0; r < 4; r++) {
          int node = re * 16 + quad * 4 + r;
          float hv = 0.f;
          if (n0 + node < NN) hv = h[(size_t)(n0 + node) * CC + n];
          sH1[node * 132 + n] = hv + (float)sA1[node * 392 + n] + acc[re][ce][r] + b2;
        }
    }
  }
  __syncthreads();

  {  // LN2 in-LDS: 8 threads/node, 16 channels each
    int node = tid >> 3, c0 = (tid & 7) * 16;
    f32x4 u[4];
    float s = 0.f, sq = 0.f;
#pragma unroll
    for (int j = 0; j < 4; j++) {
      u[j] = *(const f32x4*)(sH1 + node * 132 + c0 + j * 4);
#pragma unroll
      for (int r = 0; r < 4; r++) { s += u[j][r]; sq += u[j][r] * u[j][r]; }
    }
    s += __shfl_xor(s, 1); sq += __shfl_xor(sq, 1);
    s += __shfl_xor(s, 2); sq += __shfl_xor(sq, 2);
    s += __shfl_xor(s, 4); sq += __shfl_xor(sq, 4);
    float mu = s * (1.0f / CC);
    float var = sq * (1.0f / CC) - mu * mu;
    float rs = rsqrtf(var + 1e-5f);
#pragma unroll
    for (int j2 = 0; j2 < 2; j2++) {
      f32x4 gg0 = *(const f32x4*)(g2 + c0 + j2 * 8);
      f32x4 gg1 = *(const f32x4*)(g2 + c0 + j2 * 8 + 4);
      f32x4 bb0 = *(const f32x4*)(bt2 + c0 + j2 * 8);
      f32x4 bb1 = *(const f32x4*)(bt2 + c0 + j2 * 8 + 4);
      bf16x8 ov;
#pragma unroll
      for (int r = 0; r < 4; r++) {
        ov[r] = (bf16_t)((u[j2 * 2][r] - mu) * rs * gg0[r] + bb0[r]);
        ov[r + 4] = (bf16_t)((u[j2 * 2 + 1][r] - mu) * rs * gg1[r] + bb1[r]);
      }
      *(bf16x8*)(sLn + node * 136 + c0 + j2 * 8) = ov;
    }
  }
  __syncthreads();

  {  // GEMM3: 32x128 @ 128x256 -> silu -> sM (reuse)
    f32x4 acc[2][4];
#pragma unroll
    for (int i = 0; i < 2; i++)
#pragma unroll
      for (int j = 0; j < 4; j++) acc[i][j] = zf;
    gemm_lg<2, 128, 136, 4>(sLn, Wm1T, wave * 64, lr, quad, acc);
#pragma unroll
    for (int ce = 0; ce < 4; ce++) {
      int n = wave * 64 + ce * 16 + lr;
      float b1 = bm1[n];
#pragma unroll
      for (int re = 0; re < 2; re++)
#pragma unroll
        for (int r = 0; r < 4; r++)
          sM[(re * 16 + quad * 4 + r) * 264 + n] = (bf16_t)silu_f(acc[re][ce][r] + b1);
    }
  }
  __syncthreads();

  {  // GEMM4: 32x256 @ 256x128; out = h1 + hd2
    f32x4 acc[2][2];
#pragma unroll
    for (int i = 0; i < 2; i++) { acc[i][0] = zf; acc[i][1] = zf; }
    gemm_lg<2, 256, 264, 2>(sM, Wm2T, wave * 32, lr, quad, acc);
#pragma unroll
    for (int ce = 0; ce < 2; ce++) {
      int n = wave * 32 + ce * 16 + lr;
      float b2 = bm2[n];
#pragma unroll
      for (int re = 0; re < 2; re++)
#pragma unroll
        for (int r = 0; r < 4; r++) {
          int node = re * 16 + quad * 4 + r;
          if (n0 + node < NN)
            out[(size_t)(n0 + node) * CC + n] = sH1[node * 132 + n] + acc[re][ce][r] + b2;
        }
    }
  }
}

extern "C" void kernel_launch(void* const* d_in, const int* in_sizes, int n_in,
                              void* d_out, int out_size, void* d_ws, size_t ws_size,
                              hipStream_t stream) {
  const float* x    = (const float*)d_in[0];
  const float* h    = (const float*)d_in[1];
  const int*   ei   = (const int*)d_in[2];
  const float* We1  = (const float*)d_in[3];
  const float* be1  = (const float*)d_in[4];
  const float* We2  = (const float*)d_in[5];
  const float* be2  = (const float*)d_in[6];
  const float* Wn1  = (const float*)d_in[7];
  const float* bn1  = (const float*)d_in[8];
  const float* Wn2  = (const float*)d_in[9];
  const float* bn2  = (const float*)d_in[10];
  const float* Wm1  = (const float*)d_in[11];
  const float* bm1  = (const float*)d_in[12];
  const float* Wm2  = (const float*)d_in[13];
  const float* bm2  = (const float*)d_in[14];
  const float* g1   = (const float*)d_in[15];
  const float* bt1  = (const float*)d_in[16];
  const float* g2   = (const float*)d_in[17];
  const float* bt2  = (const float*)d_in[18];
  float* out = (float*)d_out;

  char* wp = (char*)d_ws;
  size_t off = 0;
  auto alloc = [&](size_t bytes) -> void* {
    void* p = wp + off;
    off = (off + bytes + 255) & ~(size_t)255;
    return p;
  };

  bf16_t* hn16   = (bf16_t*)alloc((size_t)NN * CC * 2);
  bf16_t* PQ     = (bf16_t*)alloc((size_t)NN * 512 * 2);
  float*  sums   = (float*)alloc((size_t)NN * HH * 4);
  int*    cnt    = (int*)alloc((size_t)NN * 4);
  int*    cursor = (int*)alloc((size_t)NN * 4);
  uint4*  edat   = (uint4*)alloc((size_t)(EBLOCKS * ETILE) * 16);
  bf16_t* We1T   = (bf16_t*)alloc(256 * 256 * 2);
  bf16_t* We2T   = (bf16_t*)alloc(256 * 256 * 2);
  bf16_t* Wn1T   = (bf16_t*)alloc(256 * 384 * 2);
  bf16_t* Wn2T   = (bf16_t*)alloc(128 * 256 * 2);
  bf16_t* Wm1T   = (bf16_t*)alloc(256 * 128 * 2);
  bf16_t* Wm2T   = (bf16_t*)alloc(128 * 256 * 2);

  prep_kernel<<<3791, 256, 0, stream>>>(We1, We2, Wn1, Wn2, Wm1, Wm2,
                                        We1T, We2T, Wn1T, Wn2T, Wm1T, Wm2T,
                                        sums, cnt, edat);

  node_pre_kernel<<<NN / 16, 256, 0, stream>>>(h, g1, bt1, We1T, be1, hn16, PQ);

  count_kernel<<<EE / 256, 256, 0, stream>>>(ei, cnt);
  scan_kernel<<<1, 1024, 0, stream>>>(cnt, cursor);
  scatter_kernel<<<EE / 256, 256, 0, stream>>>(ei, x, cursor, edat);

  // edge work split into 3 dispatches (~36 µs each) so the rocprof top-5
  // surfaces the second-tier kernels (node_fused / node_pre / scatter).
  edge_mlp_kernel<<<1112, 256, 0, stream>>>(edat, PQ, We1 + 256 * 256,
                                            We2T, be2, sums, 0);
  edge_mlp_kernel<<<1112, 256, 0, stream>>>(edat, PQ, We1 + 256 * 256,
                                            We2T, be2, sums, 1112);
  edge_mlp_kernel<<<1110, 256, 0, stream>>>(edat, PQ, We1 + 256 * 256,
                                            We2T, be2, sums, 2224);

  node_fused_kernel<<<(NN + 31) / 32, 256, 0, stream>>>(h, hn16, sums, cnt,
                                                        Wn1T, bn1, Wn2T, bn2,
                                                        g2, bt2, Wm1T, bm1, Wm2T, bm2, out);
}

// Round 11
// 296.866 us; speedup vs baseline: 2.9008x; 1.0501x over previous
//
#include <hip/hip_runtime.h>

#define NN 10000
#define CC 128
#define HH 256
#define EE 320000
#define ETILE 96
#define EBLOCKS 3334  // ceil(EE/96); pad = 64 zero-edges

typedef __bf16 bf16_t;
typedef __bf16 bf16x8 __attribute__((ext_vector_type(8)));
typedef __bf16 bf16x4 __attribute__((ext_vector_type(4)));
typedef float f32x4 __attribute__((ext_vector_type(4)));

__device__ __forceinline__ float silu_f(float v) {
#if __has_builtin(__builtin_amdgcn_rcpf)
  return v * __builtin_amdgcn_rcpf(1.0f + __expf(-v));
#else
  return v / (1.0f + __expf(-v));
#endif
}

// ---- GEMM slab helper (16x16x32 bf16 MFMA) ----
// Fragment layouts (guide §3, m89-verified):
//   1st operand: lane holds A[m=lane&15][k=quad*8+j]
//   2nd operand: lane holds B[k=quad*8+j][n=lane&15]
//   C/D: col(n)=lane&15, row(m)=quad*4+reg
template<int RE, int KD, int SA, int NT>
__device__ __forceinline__ void gemm_lg(const bf16_t* sAa, const bf16_t* __restrict__ BT,
                                        int nwavebase, int lr, int quad, f32x4 acc[RE][NT]) {
  for (int kk = 0; kk < KD; kk += 32) {
    bf16x8 a[RE]; bf16x8 b[NT];
#pragma unroll
    for (int re = 0; re < RE; re++)
      a[re] = *(const bf16x8*)(sAa + (re * 16 + lr) * SA + kk + quad * 8);
#pragma unroll
    for (int ce = 0; ce < NT; ce++)
      b[ce] = *(const bf16x8*)(BT + (size_t)(nwavebase + ce * 16 + lr) * KD + kk + quad * 8);
#pragma unroll
    for (int re = 0; re < RE; re++)
#pragma unroll
      for (int ce = 0; ce < NT; ce++)
        acc[re][ce] = __builtin_amdgcn_mfma_f32_16x16x32_bf16(a[re], b[ce], acc[re][ce], 0, 0, 0);
  }
}

// ---------- prep: 6 weight transposes + zero sums/cnt/edat-pad ----------
__global__ __launch_bounds__(256) void prep_kernel(
    const float* __restrict__ We1, const float* __restrict__ We2,
    const float* __restrict__ Wn1, const float* __restrict__ Wn2,
    const float* __restrict__ Wm1, const float* __restrict__ Wm2,
    bf16_t* __restrict__ We1T, bf16_t* __restrict__ We2T,
    bf16_t* __restrict__ Wn1T, bf16_t* __restrict__ Wn2T,
    bf16_t* __restrict__ Wm1T, bf16_t* __restrict__ Wm2T,
    float* __restrict__ sums, int* __restrict__ cnt, uint4* __restrict__ edat) {
  int i = blockIdx.x * 256 + threadIdx.x;
  if (i < 327680) {
    const float* src; bf16_t* dst; int K, Nc, idx;
    if      (i < 65536)  { src = We1; dst = We1T; K = 256; Nc = 256; idx = i; }
    else if (i < 131072) { src = We2; dst = We2T; K = 256; Nc = 256; idx = i - 65536; }
    else if (i < 229376) { src = Wn1; dst = Wn1T; K = 384; Nc = 256; idx = i - 131072; }
    else if (i < 262144) { src = Wn2; dst = Wn2T; K = 256; Nc = 128; idx = i - 229376; }
    else if (i < 294912) { src = Wm1; dst = Wm1T; K = 128; Nc = 256; idx = i - 262144; }
    else                 { src = Wm2; dst = Wm2T; K = 256; Nc = 128; idx = i - 294912; }
    int n = idx / K, k = idx - n * K;
    dst[idx] = (bf16_t)src[(size_t)k * Nc + n];
  } else if (i < 327680 + 640000) {  // NN*HH/4 f32x4 zeros
    f32x4 z = {0.f, 0.f, 0.f, 0.f};
    ((f32x4*)sums)[i - 327680] = z;
  } else if (i < 327680 + 640000 + 2500) {  // NN/4 int4 zeros
    int4 z = {0, 0, 0, 0};
    ((int4*)cnt)[i - 967680] = z;
  } else if (i < 327680 + 640000 + 2500 + 64) {  // zero pad edges
    uint4 z = {0u, 0u, 0u, 0u};
    edat[EE + (i - 970180)] = z;
  }
}

// ---------- fused LN1 + P/Q precompute, 16 nodes/block, 625 blocks ----------
__global__ __launch_bounds__(256, 4) void node_pre_kernel(
    const float* __restrict__ h, const float* __restrict__ g1,
    const float* __restrict__ bt1,
    const bf16_t* __restrict__ We1T, const float* __restrict__ be1,
    bf16_t* __restrict__ hn16, bf16_t* __restrict__ PQ) {
  __shared__ __align__(16) bf16_t sHn[16 * 136];
  int tid = threadIdx.x;
  int lane = tid & 63, wave = tid >> 6;
  int lr = lane & 15, quad = lane >> 4;
  int n0 = blockIdx.x * 16;  // 625 * 16 = NN exact

  // LN1: 16 threads/node, 8 channels each
  {
    int node = tid >> 4, c0 = (tid & 15) * 8;
    size_t base = (size_t)(n0 + node) * CC;
    f32x4 u0 = *(const f32x4*)(h + base + c0);
    f32x4 u1 = *(const f32x4*)(h + base + c0 + 4);
    float s = 0.f, sq = 0.f;
#pragma unroll
    for (int j = 0; j < 4; j++) { s += u0[j] + u1[j]; sq += u0[j] * u0[j] + u1[j] * u1[j]; }
#pragma unroll
    for (int o = 8; o > 0; o >>= 1) { s += __shfl_xor(s, o); sq += __shfl_xor(sq, o); }
    float mu = s * (1.0f / CC);
    float var = sq * (1.0f / CC) - mu * mu;
    float rs = rsqrtf(var + 1e-5f);
    f32x4 gg0 = *(const f32x4*)(g1 + c0), gg1 = *(const f32x4*)(g1 + c0 + 4);
    f32x4 bb0 = *(const f32x4*)(bt1 + c0), bb1 = *(const f32x4*)(bt1 + c0 + 4);
    bf16x8 ov;
#pragma unroll
    for (int j = 0; j < 4; j++) {
      ov[j] = (bf16_t)((u0[j] - mu) * rs * gg0[j] + bb0[j]);
      ov[j + 4] = (bf16_t)((u1[j] - mu) * rs * gg1[j] + bb1[j]);
    }
    *(bf16x8*)(sHn + node * 136 + c0) = ov;
    *(bf16x8*)(hn16 + base + c0) = ov;
  }
  __syncthreads();

  // PQ GEMM: waves 0-1 -> P (We1T k-cols 0:128), waves 2-3 -> Q (k-cols 128:256).
  bool isQ = wave >= 2;
  int rbase = (wave & 1) * 128;
  int koff = isQ ? 128 : 0;
  f32x4 zf = {0.f, 0.f, 0.f, 0.f};
  f32x4 acc[8];
#pragma unroll
  for (int i = 0; i < 8; i++) acc[i] = zf;
  for (int kk = 0; kk < 128; kk += 32) {
    bf16x8 b = *(const bf16x8*)(sHn + lr * 136 + kk + quad * 8);
    bf16x8 a[8];
#pragma unroll
    for (int re = 0; re < 8; re++)
      a[re] = *(const bf16x8*)(We1T + (size_t)(rbase + re * 16 + lr) * 256 + koff + kk + quad * 8);
#pragma unroll
    for (int re = 0; re < 8; re++)
      acc[re] = __builtin_amdgcn_mfma_f32_16x16x32_bf16(a[re], b, acc[re], 0, 0, 0);
  }
  // C: col = node (lr), row = channel rbase + re*16 + quad*4 + r
#pragma unroll
  for (int re = 0; re < 8; re++) {
    int cb = rbase + re * 16 + quad * 4;
    f32x4 bb = isQ ? zf : *(const f32x4*)(be1 + cb);
    bf16x4 o;
#pragma unroll
    for (int r = 0; r < 4; r++) o[r] = (bf16_t)(acc[re][r] + bb[r]);
    *(bf16x4*)(PQ + (size_t)(n0 + lr) * 512 + (isQ ? 256 : 0) + cb) = o;
  }
}

// ---------- CSR build ----------
__global__ __launch_bounds__(256) void count_kernel(const int* __restrict__ ei, int* __restrict__ cnt) {
  int e = blockIdx.x * 256 + threadIdx.x;
  atomicAdd(&cnt[ei[EE + e]], 1);
}

// single-pass scan: thread owns 10 contiguous elements
__global__ __launch_bounds__(1024) void scan_kernel(const int* __restrict__ cnt, int* __restrict__ cursor) {
  __shared__ int wsum[16];
  int tid = threadIdx.x, wave = tid >> 6, lane = tid & 63;
  int base = tid * 10;
  int v[10]; int S = 0;
#pragma unroll
  for (int j = 0; j < 10; j++) {
    int i = base + j;
    v[j] = (i < NN) ? cnt[i] : 0;
    S += v[j];
  }
  int s = S;
#pragma unroll
  for (int off = 1; off < 64; off <<= 1) { int t = __shfl_up(s, off); if (lane >= off) s += t; }
  if (lane == 63) wsum[wave] = s;
  __syncthreads();
  if (tid < 16) {
    int ws = wsum[tid];
#pragma unroll
    for (int off = 1; off < 16; off <<= 1) { int t = __shfl_up(ws, off); if (tid >= off) ws += t; }
    wsum[tid] = ws;
  }
  __syncthreads();
  int ex = ((wave > 0) ? wsum[wave - 1] : 0) + s - S;  // exclusive prefix of this chunk
#pragma unroll
  for (int j = 0; j < 10; j++) {
    int i = base + j;
    if (i < NN) cursor[i] = ex;
    ex += v[j];
  }
}

__global__ __launch_bounds__(256) void scatter_kernel(const int* __restrict__ ei,
                                                      const float* __restrict__ x,
                                                      int* __restrict__ cursor,
                                                      uint4* __restrict__ edat) {
  int e = blockIdx.x * 256 + threadIdx.x;
  int r = ei[e], c = ei[EE + e];
  float dx = x[3 * r] - x[3 * c];
  float dy = x[3 * r + 1] - x[3 * c + 1];
  float dz = x[3 * r + 2] - x[3 * c + 2];
  float d = sqrtf(dx * dx + dy * dy + dz * dz);
  float cc = (d <= 5.0f) ? 0.5f * (cosf(d * 0.6283185307179586f) + 1.0f) : 0.0f;
  int pos = atomicAdd(&cursor[c], 1);
  uint4 v = {(unsigned)r, (unsigned)c, __float_as_uint(d), __float_as_uint(cc)};
  edat[pos] = v;
}

// ---------- edge kernel: 96-edge tiles, 512 threads / 8 waves ----------
// Each wave: 32 channels x 96 edges -> acc[6][2] = 48 AGPR. Peak pressure
// ~110 regs (acc NOT live during staging) -> fits (512,4)'s 128 budget ->
// 2 blocks/CU = 16 waves (2x the R7 kernel's 8). If regs >128 -> 1 block =
// R7-equivalent 8 waves (bounded downside). Watch FETCH/WRITE for spill.
__global__ __launch_bounds__(512, 4) void edge_mlp_kernel(
    const uint4* __restrict__ edat, const bf16_t* __restrict__ PQ,
    const float* __restrict__ We1last,
    const bf16_t* __restrict__ We2T, const float* __restrict__ be2,
    float* __restrict__ sums) {
  __shared__ __align__(16) bf16_t sM1[ETILE * 264];  // 50688 B
  __shared__ int sRow[ETILE], sCol[ETILE];
  __shared__ float sD[ETILE], sCc[ETILE];
  __shared__ unsigned long long sMaskA;
  __shared__ unsigned sMaskB;
  int tid = threadIdx.x;
  int lane = tid & 63, wave = tid >> 6;  // 8 waves
  int lr = lane & 15, quad = lane >> 4;
  int e0 = blockIdx.x * ETILE;

  if (tid < ETILE) {
    uint4 v = edat[e0 + tid];
    sRow[tid] = (int)v.x; sCol[tid] = (int)v.y;
    sD[tid] = __uint_as_float(v.z); sCc[tid] = __uint_as_float(v.w);
  }
  __syncthreads();

  if (tid < ETILE) {  // waves 0,1 only; wave-1 lanes 0-31 carry edges 64-95
    int fl = (tid > 0) && (sCol[tid] != sCol[tid - 1]);
    unsigned long long m = __ballot(fl);
    if (tid == 0) sMaskA = m;
    if (tid == 64) sMaskB = (unsigned)m;
  }

  // m1[e][k] = silu(P[row][k] + Q[col][k] + d*wl[k]): 3072 chunks / 512 thr = 6
#pragma unroll 3
  for (int i = 0; i < 6; i++) {
    int o = tid + i * 512;
    int e = o >> 5, q = o & 31;
    int k0 = q * 8;
    int row = sRow[e], col = sCol[e];
    float d = sD[e];
    bf16x8 pv = *(const bf16x8*)(PQ + (size_t)row * 512 + k0);
    bf16x8 qv = *(const bf16x8*)(PQ + (size_t)col * 512 + 256 + k0);
    f32x4 wl0 = *(const f32x4*)(We1last + k0);
    f32x4 wl1 = *(const f32x4*)(We1last + k0 + 4);
    bf16x8 m;
#pragma unroll
    for (int j = 0; j < 4; j++) {
      m[j] = (bf16_t)silu_f((float)pv[j] + (float)qv[j] + d * wl0[j]);
      m[j + 4] = (bf16_t)silu_f((float)pv[j + 4] + (float)qv[j + 4] + d * wl1[j]);
    }
    *(bf16x8*)(sM1 + e * 264 + k0) = m;
  }
  __syncthreads();

  // GEMM2: m1 (96 x 256) @ We2 -> this wave's 32 channels
  f32x4 zf = {0.f, 0.f, 0.f, 0.f};
  f32x4 acc[6][2];
#pragma unroll
  for (int i = 0; i < 6; i++) { acc[i][0] = zf; acc[i][1] = zf; }
  for (int kk = 0; kk < 256; kk += 32) {
    bf16x8 a[6]; bf16x8 b[2];
#pragma unroll
    for (int re = 0; re < 6; re++)
      a[re] = *(const bf16x8*)(sM1 + (re * 16 + lr) * 264 + kk + quad * 8);
#pragma unroll
    for (int ce = 0; ce < 2; ce++)
      b[ce] = *(const bf16x8*)(We2T + (size_t)(wave * 32 + ce * 16 + lr) * 256 + kk + quad * 8);
#pragma unroll
    for (int re = 0; re < 6; re++)
#pragma unroll
      for (int ce = 0; ce < 2; ce++)
        acc[re][ce] = __builtin_amdgcn_mfma_f32_16x16x32_bf16(a[re], b[ce], acc[re][ce], 0, 0, 0);
  }

  // in-register epilogue: silu(acc+be2)*cc  (edge e = re*16+quad*4+r)
  float be2v[2];
#pragma unroll
  for (int ce = 0; ce < 2; ce++) be2v[ce] = be2[wave * 32 + ce * 16 + lr];
#pragma unroll
  for (int re = 0; re < 6; re++) {
    f32x4 cc = *(const f32x4*)(sCc + re * 16 + quad * 4);
#pragma unroll
    for (int ce = 0; ce < 2; ce++)
#pragma unroll
      for (int r = 0; r < 4; r++)
        acc[re][ce][r] = silu_f(acc[re][ce][r] + be2v[ce]) * cc[r];
  }

  // register segmented reduction with static tile-skip (wave-uniform branches).
  // 64-bit mask arithmetic throughout (lo<=95 -> shifts well-defined).
  {
    unsigned long long mA = sMaskA;
    unsigned long long mB = (unsigned long long)sMaskB;  // bit i = edge 64+i
    int lo = 0;
    while (lo < ETILE) {
      int hi;
      if (lo < 63) {
        unsigned long long t = mA & (~0ull << (lo + 1));
        hi = t ? (__ffsll((long long)t) - 1)
               : (mB ? 64 + __ffsll((long long)mB) - 1 : ETILE);
      } else {
        unsigned long long t1 = mB & (~0ull << (lo - 63));
        hi = t1 ? 64 + __ffsll((long long)t1) - 1 : ETILE;
      }
      float tv0 = 0.f, tv1 = 0.f;
#pragma unroll
      for (int re = 0; re < 6; re++) {
        int t0 = re * 16, t1e = t0 + 16;
        if (t1e <= lo || t0 >= hi) continue;  // tile outside segment (scalar skip)
        if (t0 >= lo && t1e <= hi) {          // tile fully inside: unmasked adds
#pragma unroll
          for (int r = 0; r < 4; r++) { tv0 += acc[re][0][r]; tv1 += acc[re][1][r]; }
        } else {                              // straddles boundary: masked adds
          int eb = t0 + quad * 4;
#pragma unroll
          for (int r = 0; r < 4; r++) {
            int e = eb + r;
            bool in = (e >= lo) && (e < hi);
            tv0 += in ? acc[re][0][r] : 0.0f;
            tv1 += in ? acc[re][1][r] : 0.0f;
          }
        }
      }
      tv0 += __shfl_xor(tv0, 16); tv0 += __shfl_xor(tv0, 32);
      tv1 += __shfl_xor(tv1, 16); tv1 += __shfl_xor(tv1, 32);
      if (quad == 0) {
        int colv = sCol[lo];
        atomicAdd(&sums[(size_t)colv * HH + wave * 32 + lr], tv0);
        atomicAdd(&sums[(size_t)colv * HH + wave * 32 + 16 + lr], tv1);
      }
      lo = hi;
    }
  }
}

// ---------- fused node pipeline: 32 nodes/block, 313 blocks ----------
__global__ __launch_bounds__(256, 2) void node_fused_kernel(
    const float* __restrict__ h, const bf16_t* __restrict__ hn16,
    const float* __restrict__ sums, const int* __restrict__ cnt,
    const bf16_t* __restrict__ Wn1T, const float* __restrict__ bn1,
    const bf16_t* __restrict__ Wn2T, const float* __restrict__ bn2,
    const float* __restrict__ g2, const float* __restrict__ bt2,
    const bf16_t* __restrict__ Wm1T, const float* __restrict__ bm1,
    const bf16_t* __restrict__ Wm2T, const float* __restrict__ bm2,
    float* __restrict__ out) {
  __shared__ __align__(16) bf16_t sA1[32 * 392];   // 25088 B
  __shared__ __align__(16) bf16_t sM[32 * 264];    // 16896 B
  __shared__ __align__(16) float sH1[32 * 132];    // 16896 B
  __shared__ __align__(16) bf16_t sLn[32 * 136];   // 8704 B
  __shared__ float sRc[32];
  int tid = threadIdx.x;
  int lane = tid & 63, wave = tid >> 6;
  int lr = lane & 15, quad = lane >> 4;
  int n0 = blockIdx.x * 32;  // 313 blocks; last has 16 live nodes

  if (tid < 32) {
    int node = n0 + tid;
    sRc[tid] = (node < NN) ? 1.0f / fmaxf((float)cnt[node], 1.0f) : 0.0f;
  }
  __syncthreads();

  // stage A1 = [hn16 | sums*rc]: 32 nodes x 48 16B-chunks, 6/thread
#pragma unroll
  for (int i = 0; i < 6; i++) {
    int o = tid + i * 256;
    int e = o / 48, q = o - e * 48;
    int node = n0 + e;
    if (q < 16) {
      uint4 v = {0u, 0u, 0u, 0u};
      if (node < NN) v = *(const uint4*)(hn16 + (size_t)node * CC + q * 8);
      *(uint4*)(sA1 + e * 392 + q * 8) = v;
    } else {
      bf16x8 bv = {};
      if (node < NN) {
        float rc = sRc[e];
        const float* sp = sums + (size_t)node * HH + (q - 16) * 8;
#pragma unroll
        for (int k2 = 0; k2 < 8; k2++) bv[k2] = (bf16_t)(sp[k2] * rc);
      }
      *(bf16x8*)(sA1 + e * 392 + 128 + (q - 16) * 8) = bv;
    }
  }
  __syncthreads();

  f32x4 zf = {0.f, 0.f, 0.f, 0.f};
  {  // GEMM1: 32x384 @ 384x256 -> silu -> sM
    f32x4 acc[2][4];
#pragma unroll
    for (int i = 0; i < 2; i++)
#pragma unroll
      for (int j = 0; j < 4; j++) acc[i][j] = zf;
    gemm_lg<2, 384, 392, 4>(sA1, Wn1T, wave * 64, lr, quad, acc);
#pragma unroll
    for (int ce = 0; ce < 4; ce++) {
      int n = wave * 64 + ce * 16 + lr;
      float b1 = bn1[n];
#pragma unroll
      for (int re = 0; re < 2; re++)
#pragma unroll
        for (int r = 0; r < 4; r++)
          sM[(re * 16 + quad * 4 + r) * 264 + n] = (bf16_t)silu_f(acc[re][ce][r] + b1);
    }
  }
  __syncthreads();

  {  // GEMM2: 32x256 @ 256x128; h1 = h + hn + hd -> sH1
    f32x4 acc[2][2];
#pragma unroll
    for (int i = 0; i < 2; i++) { acc[i][0] = zf; acc[i][1] = zf; }
    gemm_lg<2, 256, 264, 2>(sM, Wn2T, wave * 32, lr, quad, acc);
#pragma unroll
    for (int ce = 0; ce < 2; ce++) {
      int n = wave * 32 + ce * 16 + lr;
      float b2 = bn2[n];
#pragma unroll
      for (int re = 0; re < 2; re++)
#pragma unroll
        for (int r = 0; r < 4; r++) {
          int node = re * 16 + quad * 4 + r;
          float hv = 0.f;
          if (n0 + node < NN) hv = h[(size_t)(n0 + node) * CC + n];
          sH1[node * 132 + n] = hv + (float)sA1[node * 392 + n] + acc[re][ce][r] + b2;
        }
    }
  }
  __syncthreads();

  {  // LN2 in-LDS: 8 threads/node, 16 channels each
    int node = tid >> 3, c0 = (tid & 7) * 16;
    f32x4 u[4];
    float s = 0.f, sq = 0.f;
#pragma unroll
    for (int j = 0; j < 4; j++) {
      u[j] = *(const f32x4*)(sH1 + node * 132 + c0 + j * 4);
#pragma unroll
      for (int r = 0; r < 4; r++) { s += u[j][r]; sq += u[j][r] * u[j][r]; }
    }
    s += __shfl_xor(s, 1); sq += __shfl_xor(sq, 1);
    s += __shfl_xor(s, 2); sq += __shfl_xor(sq, 2);
    s += __shfl_xor(s, 4); sq += __shfl_xor(sq, 4);
    float mu = s * (1.0f / CC);
    float var = sq * (1.0f / CC) - mu * mu;
    float rs = rsqrtf(var + 1e-5f);
#pragma unroll
    for (int j2 = 0; j2 < 2; j2++) {
      f32x4 gg0 = *(const f32x4*)(g2 + c0 + j2 * 8);
      f32x4 gg1 = *(const f32x4*)(g2 + c0 + j2 * 8 + 4);
      f32x4 bb0 = *(const f32x4*)(bt2 + c0 + j2 * 8);
      f32x4 bb1 = *(const f32x4*)(bt2 + c0 + j2 * 8 + 4);
      bf16x8 ov;
#pragma unroll
      for (int r = 0; r < 4; r++) {
        ov[r] = (bf16_t)((u[j2 * 2][r] - mu) * rs * gg0[r] + bb0[r]);
        ov[r + 4] = (bf16_t)((u[j2 * 2 + 1][r] - mu) * rs * gg1[r] + bb1[r]);
      }
      *(bf16x8*)(sLn + node * 136 + c0 + j2 * 8) = ov;
    }
  }
  __syncthreads();

  {  // GEMM3: 32x128 @ 128x256 -> silu -> sM (reuse)
    f32x4 acc[2][4];
#pragma unroll
    for (int i = 0; i < 2; i++)
#pragma unroll
      for (int j = 0; j < 4; j++) acc[i][j] = zf;
    gemm_lg<2, 128, 136, 4>(sLn, Wm1T, wave * 64, lr, quad, acc);
#pragma unroll
    for (int ce = 0; ce < 4; ce++) {
      int n = wave * 64 + ce * 16 + lr;
      float b1 = bm1[n];
#pragma unroll
      for (int re = 0; re < 2; re++)
#pragma unroll
        for (int r = 0; r < 4; r++)
          sM[(re * 16 + quad * 4 + r) * 264 + n] = (bf16_t)silu_f(acc[re][ce][r] + b1);
    }
  }
  __syncthreads();

  {  // GEMM4: 32x256 @ 256x128; out = h1 + hd2
    f32x4 acc[2][2];
#pragma unroll
    for (int i = 0; i < 2; i++) { acc[i][0] = zf; acc[i][1] = zf; }
    gemm_lg<2, 256, 264, 2>(sM, Wm2T, wave * 32, lr, quad, acc);
#pragma unroll
    for (int ce = 0; ce < 2; ce++) {
      int n = wave * 32 + ce * 16 + lr;
      float b2 = bm2[n];
#pragma unroll
      for (int re = 0; re < 2; re++)
#pragma unroll
        for (int r = 0; r < 4; r++) {
          int node = re * 16 + quad * 4 + r;
          if (n0 + node < NN)
            out[(size_t)(n0 + node) * CC + n] = sH1[node * 132 + n] + acc[re][ce][r] + b2;
        }
    }
  }
}

extern "C" void kernel_launch(void* const* d_in, const int* in_sizes, int n_in,
                              void* d_out, int out_size, void* d_ws, size_t ws_size,
                              hipStream_t stream) {
  const float* x    = (const float*)d_in[0];
  const float* h    = (const float*)d_in[1];
  const int*   ei   = (const int*)d_in[2];
  const float* We1  = (const float*)d_in[3];
  const float* be1  = (const float*)d_in[4];
  const float* We2  = (const float*)d_in[5];
  const float* be2  = (const float*)d_in[6];
  const float* Wn1  = (const float*)d_in[7];
  const float* bn1  = (const float*)d_in[8];
  const float* Wn2  = (const float*)d_in[9];
  const float* bn2  = (const float*)d_in[10];
  const float* Wm1  = (const float*)d_in[11];
  const float* bm1  = (const float*)d_in[12];
  const float* Wm2  = (const float*)d_in[13];
  const float* bm2  = (const float*)d_in[14];
  const float* g1   = (const float*)d_in[15];
  const float* bt1  = (const float*)d_in[16];
  const float* g2   = (const float*)d_in[17];
  const float* bt2  = (const float*)d_in[18];
  float* out = (float*)d_out;

  char* wp = (char*)d_ws;
  size_t off = 0;
  auto alloc = [&](size_t bytes) -> void* {
    void* p = wp + off;
    off = (off + bytes + 255) & ~(size_t)255;
    return p;
  };

  bf16_t* hn16   = (bf16_t*)alloc((size_t)NN * CC * 2);
  bf16_t* PQ     = (bf16_t*)alloc((size_t)NN * 512 * 2);
  float*  sums   = (float*)alloc((size_t)NN * HH * 4);
  int*    cnt    = (int*)alloc((size_t)NN * 4);
  int*    cursor = (int*)alloc((size_t)NN * 4);
  uint4*  edat   = (uint4*)alloc((size_t)(EBLOCKS * ETILE) * 16);
  bf16_t* We1T   = (bf16_t*)alloc(256 * 256 * 2);
  bf16_t* We2T   = (bf16_t*)alloc(256 * 256 * 2);
  bf16_t* Wn1T   = (bf16_t*)alloc(256 * 384 * 2);
  bf16_t* Wn2T   = (bf16_t*)alloc(128 * 256 * 2);
  bf16_t* Wm1T   = (bf16_t*)alloc(256 * 128 * 2);
  bf16_t* Wm2T   = (bf16_t*)alloc(128 * 256 * 2);

  prep_kernel<<<3791, 256, 0, stream>>>(We1, We2, Wn1, Wn2, Wm1, Wm2,
                                        We1T, We2T, Wn1T, Wn2T, Wm1T, Wm2T,
                                        sums, cnt, edat);

  node_pre_kernel<<<NN / 16, 256, 0, stream>>>(h, g1, bt1, We1T, be1, hn16, PQ);

  count_kernel<<<EE / 256, 256, 0, stream>>>(ei, cnt);
  scan_kernel<<<1, 1024, 0, stream>>>(cnt, cursor);
  scatter_kernel<<<EE / 256, 256, 0, stream>>>(ei, x, cursor, edat);

  edge_mlp_kernel<<<EBLOCKS, 512, 0, stream>>>(edat, PQ, We1 + 256 * 256,
                                               We2T, be2, sums);

  node_fused_kernel<<<(NN + 31) / 32, 256, 0, stream>>>(h, hn16, sums, cnt,
                                                        Wn1T, bn1, Wn2T, bn2,
                                                        g2, bt2, Wm1T, bm1, Wm2T, bm2, out);
}